// Round 9
// baseline (2265.849 us; speedup 1.0000x reference)
//
#include <hip/hip_runtime.h>
#include <stdint.h>

#define N_NODES 100000
#define E_EDGES 1600000
#define INDIM 128
#define DD 64
#define HH 16
#define SS 8
#define HS 128            // H*S
#define GG 512
#define PENN 128
#define CC 10
#define F_OUT 384
#define BN_EPS 1e-5f

// ---------------- degree (out-degree over row + self loop) ----------------
__global__ void k_init_deg(float* deg){
    int n = blockIdx.x*256 + threadIdx.x;
    if(n < N_NODES) deg[n] = 1.0f;   // self loop
}

__global__ void k_deg(const int* __restrict__ row, float* deg){
    int e = blockIdx.x*256 + threadIdx.x;
    if(e < E_EDGES) atomicAdd(&deg[row[e]], 1.0f);
}

// ---------------- CSR-by-col build (once per launch, reused by both gathers) ----------------
__global__ void k_zero_cnt(int* cnt){
    int n = blockIdx.x*256 + threadIdx.x;
    if(n < N_NODES) cnt[n] = 0;
}

__global__ void k_hist(const int* __restrict__ col, int* __restrict__ cnt){
    int e = blockIdx.x*256 + threadIdx.x;
    if(e < E_EDGES) atomicAdd(&cnt[col[e]], 1);
}

// single-block exclusive scan over cnt -> rowptr[0..N], cursor copy
__global__ __launch_bounds__(1024) void k_scan(const int* __restrict__ cnt,
                                               int* __restrict__ rowptr,
                                               int* __restrict__ cursor){
    __shared__ int buf[1024];
    __shared__ int carry;
    int t = threadIdx.x;
    if(t == 0) carry = 0;
    __syncthreads();
    for(int base = 0; base < N_NODES; base += 1024){
        int i = base + t;
        int v = (i < N_NODES) ? cnt[i] : 0;
        buf[t] = v;
        __syncthreads();
        for(int off = 1; off < 1024; off <<= 1){
            int add = (t >= off) ? buf[t - off] : 0;
            __syncthreads();
            buf[t] += add;
            __syncthreads();
        }
        int excl = buf[t] - v;
        int total = buf[1023];
        int base_c = carry;
        if(i < N_NODES){ rowptr[i] = base_c + excl; cursor[i] = base_c + excl; }
        __syncthreads();
        if(t == 0) carry = base_c + total;
        __syncthreads();
    }
    if(t == 0) rowptr[N_NODES] = carry;   // == E_EDGES
}

__global__ void k_fill(const int* __restrict__ row, const int* __restrict__ col,
                       int* __restrict__ cursor, int* __restrict__ erow){
    int e = blockIdx.x*256 + threadIdx.x;
    if(e < E_EDGES){
        int idx = atomicAdd(&cursor[col[e]], 1);
        erow[idx] = row[e];
    }
}

// ---------------- xh = sigmoid(x @ fc_w^T + b); y0 = xh/deg ----------------
// weights in registers: lane d holds fc_w[d][0..127]; x row read as wave-uniform float4 broadcasts.
__global__ __launch_bounds__(256) void k_xh(const float* __restrict__ x, const float* __restrict__ fc_w,
                     const float* __restrict__ fc_b, const float* __restrict__ deg,
                     float* __restrict__ xh, float* __restrict__ ybuf){
    int lane = threadIdx.x & 63;
    int wave = (blockIdx.x*256 + threadIdx.x) >> 6;
    int nwaves = gridDim.x * 4;
    float w[INDIM];
    const float4* wr = (const float4*)(fc_w + (size_t)lane*INDIM);
    #pragma unroll
    for(int q = 0; q < INDIM/4; ++q){
        float4 v = wr[q];
        w[4*q+0] = v.x; w[4*q+1] = v.y; w[4*q+2] = v.z; w[4*q+3] = v.w;
    }
    float bias = fc_b[lane];
    #pragma unroll 1
    for(int n = wave; n < N_NODES; n += nwaves){
        const float4* xr = (const float4*)(x + (size_t)n*INDIM);
        float acc = bias;
        #pragma unroll
        for(int q = 0; q < INDIM/4; ++q){
            float4 v = xr[q];
            acc = fmaf(v.x, w[4*q+0], acc);
            acc = fmaf(v.y, w[4*q+1], acc);
            acc = fmaf(v.z, w[4*q+2], acc);
            acc = fmaf(v.w, w[4*q+3], acc);
        }
        float s = 1.0f/(1.0f + expf(-acc));
        size_t o = (size_t)n*DD + lane;
        xh[o] = s;
        ybuf[o] = s / deg[n];
    }
}

// ---------------- gather-based aggregation: agg[n] = y[n] + sum_{e: col==n} y[row[e]] ----------------
// one wave per node, lane = d. No atomics; erow run order only permutes the FP sum.
__global__ __launch_bounds__(256) void k_gather(const int* __restrict__ rowptr, const int* __restrict__ erow,
                        const float* __restrict__ y, float* __restrict__ agg){
    int lane = threadIdx.x & 63;
    int wave = (blockIdx.x*256 + threadIdx.x) >> 6;
    int nwaves = gridDim.x * 4;
    #pragma unroll 1
    for(int n = wave; n < N_NODES; n += nwaves){
        int b = rowptr[n], en = rowptr[n+1];
        float acc = y[(size_t)n*DD + lane];    // self loop
        #pragma unroll 1
        for(int j = b; j < en; ++j){
            int rr = erow[j];
            acc += y[(size_t)rr*DD + lane];
        }
        agg[(size_t)n*DD + lane] = acc;
    }
}

// ---------------- cur = agg @ w^T + b ; optionally y_next = cur/deg ----------------
// weights in registers: lane d holds w[d][0..63]
__global__ __launch_bounds__(256) void k_lin(const float* __restrict__ agg, const float* __restrict__ w_,
                     const float* __restrict__ b, const float* __restrict__ deg,
                     float* __restrict__ cur, float* __restrict__ ynext, int make_next){
    int lane = threadIdx.x & 63;
    int wave = (blockIdx.x*256 + threadIdx.x) >> 6;
    int nwaves = gridDim.x * 4;
    float w[DD];
    const float4* wr = (const float4*)(w_ + (size_t)lane*DD);
    #pragma unroll
    for(int q = 0; q < DD/4; ++q){
        float4 v = wr[q];
        w[4*q+0] = v.x; w[4*q+1] = v.y; w[4*q+2] = v.z; w[4*q+3] = v.w;
    }
    float bias = b[lane];
    #pragma unroll 1
    for(int n = wave; n < N_NODES; n += nwaves){
        const float4* ar = (const float4*)(agg + (size_t)n*DD);
        float acc = bias;
        #pragma unroll
        for(int q = 0; q < DD/4; ++q){
            float4 v = ar[q];
            acc = fmaf(v.x, w[4*q+0], acc);
            acc = fmaf(v.y, w[4*q+1], acc);
            acc = fmaf(v.z, w[4*q+2], acc);
            acc = fmaf(v.w, w[4*q+3], acc);
        }
        size_t o = (size_t)n*DD + lane;
        cur[o] = acc;
        if(make_next) ynext[o] = acc / deg[n];
    }
}

// ---------------- z1 = A@z0, z2 = A@z1 (A from relu'd upper-tri params, symmetrized) ----------------
__global__ void k_z(const float* __restrict__ adj_hidden, const float* __restrict__ z0,
                    float* __restrict__ z1, float* __restrict__ z2){
    __shared__ float A[HH][SS][SS];
    __shared__ float zb[HH][SS][DD];
    int tid = threadIdx.x;
    for(int i = tid; i < HH*SS*SS; i += 256) ((float*)A)[i] = 0.0f;
    __syncthreads();
    for(int i = tid; i < HH*28; i += 256){
        int h = i / 28, p = i % 28;
        int iu = 0, ju = 0, cnt = 0;
        for(int a = 0; a < SS-1; ++a){
            int rl = SS-1-a;
            if(p < cnt + rl){ iu = a; ju = a + 1 + (p - cnt); break; }
            cnt += rl;
        }
        float v = adj_hidden[i];
        v = v > 0.f ? v : 0.f;
        A[h][iu][ju] = v;
        A[h][ju][iu] = v;
    }
    __syncthreads();
    for(int i = tid; i < HH*SS*DD; i += 256){
        int h = i >> 9, a = (i >> 6) & 7, d = i & 63;
        float acc = 0.f;
        #pragma unroll
        for(int bb = 0; bb < SS; ++bb) acc += A[h][a][bb] * z0[(h*SS+bb)*DD + d];
        z1[i] = acc;
        zb[h][a][d] = acc;
    }
    __syncthreads();
    for(int i = tid; i < HH*SS*DD; i += 256){
        int h = i >> 9, a = (i >> 6) & 7, d = i & 63;
        float acc = 0.f;
        #pragma unroll
        for(int bb = 0; bb < SS; ++bb) acc += A[h][a][bb] * zb[h][bb][d];
        z2[i] = acc;
    }
}

// ---------------- graph boundaries from sorted batch ----------------
__global__ void k_bounds(const int* __restrict__ batch, int* __restrict__ start){
    int n = blockIdx.x*256 + threadIdx.x;
    if(n >= N_NODES) return;
    int b = batch[n];
    int prev = (n == 0) ? -1 : batch[n-1];
    for(int g = prev + 1; g <= b; ++g) start[g] = n;
    if(n == N_NODES-1){
        for(int g = b + 1; g <= GG; ++g) start[g] = N_NODES;
    }
}

// ---------------- fused per-graph feature reduce, all 3 steps ----------------
// grid = 2*GG blocks; block = 192 threads = 3 waves (one per step i).
// block (g, half): wave i computes P_i[g][half*64 + lane] = sum_{n in g} zx*dot_i
__global__ __launch_bounds__(192) void k_feat3(const float* __restrict__ z0, const float* __restrict__ z1,
                       const float* __restrict__ z2,
                       const float* __restrict__ xh, const float* __restrict__ cur1,
                       const float* __restrict__ cur2,
                       const int* __restrict__ start, float* __restrict__ P){
    int lane = threadIdx.x & 63;
    int i = threadIdx.x >> 6;          // step 0..2
    int half = blockIdx.x & 1;
    int g = blockIdx.x >> 1;
    int hs = half*64 + lane;

    float z0r[DD], zir[DD];
    {
        const float4* p0 = (const float4*)(z0 + (size_t)hs*DD);
        #pragma unroll
        for(int q = 0; q < DD/4; ++q){
            float4 v = p0[q];
            z0r[4*q+0]=v.x; z0r[4*q+1]=v.y; z0r[4*q+2]=v.z; z0r[4*q+3]=v.w;
        }
        const float* zi = (i == 1) ? z1 : z2;
        if(i > 0){
            const float4* pi = (const float4*)(zi + (size_t)hs*DD);
            #pragma unroll
            for(int q = 0; q < DD/4; ++q){
                float4 v = pi[q];
                zir[4*q+0]=v.x; zir[4*q+1]=v.y; zir[4*q+2]=v.z; zir[4*q+3]=v.w;
            }
        }
    }
    const float* cur = (i == 0) ? xh : (i == 1 ? cur1 : cur2);

    int s0 = start[g], s1 = start[g+1];
    float acc = 0.0f;

    float cv = 0.f, xv = 0.f;
    if(s0 < s1){
        cv = cur[(size_t)s0*DD + lane];
        xv = xh[(size_t)s0*DD + lane];
    }
    #pragma unroll 1
    for(int n = s0; n < s1; ++n){
        float cvn = 0.f, xvn = 0.f;
        if(n + 1 < s1){
            cvn = cur[(size_t)(n+1)*DD + lane];
            xvn = xh[(size_t)(n+1)*DD + lane];
        }
        if(i == 0){
            float dt = 0.f;
            #pragma unroll
            for(int k = 0; k < DD; ++k){
                float bc = __shfl(cv, k);
                dt = fmaf(z0r[k], bc, dt);
            }
            acc = fmaf(dt, dt, acc);
        } else {
            float dt = 0.f, zx = 0.f;
            #pragma unroll
            for(int k = 0; k < DD; ++k){
                float bc = __shfl(cv, k);
                float bx = __shfl(xv, k);
                dt = fmaf(zir[k], bc, dt);
                zx = fmaf(z0r[k], bx, zx);
            }
            acc = fmaf(zx, dt, acc);
        }
        cv = cvn; xv = xvn;
    }
    P[((size_t)i*GG + g)*HS + hs] = acc;
}

// ---------------- scrambled reshape: out_pre[r][i*128+c] = P_i[g,h,s] ----------------
__global__ void k_outpre(const float* __restrict__ P, float* __restrict__ outp){
    int idx = blockIdx.x*256 + threadIdx.x;
    if(idx >= GG*F_OUT) return;
    int r = idx / F_OUT, j = idx % F_OUT;
    int i = j >> 7, c = j & 127;
    int g = ((r & 63) << 3) + (c >> 4);
    int h = c & 15, s = r >> 6;
    int hs = h*SS + s;
    outp[idx] = P[((size_t)i*GG + g)*HS + hs];
}

// ---------------- batchnorm stats per column (training-mode batch stats) ----------------
__global__ void k_bnstats(const float* __restrict__ outp, const float* __restrict__ gamma,
                          const float* __restrict__ beta, float* __restrict__ scale_,
                          float* __restrict__ shift_){
    int j = blockIdx.x;     // 384 columns
    int t = threadIdx.x;    // 64 threads
    float v[8];
    float sum = 0.f;
    #pragma unroll
    for(int i = 0; i < 8; ++i){ v[i] = outp[(size_t)(t*8+i)*F_OUT + j]; sum += v[i]; }
    #pragma unroll
    for(int off = 32; off; off >>= 1) sum += __shfl_down(sum, off);
    sum = __shfl(sum, 0);
    float mean = sum / (float)GG;
    float sq = 0.f;
    #pragma unroll
    for(int i = 0; i < 8; ++i){ float d = v[i] - mean; sq = fmaf(d, d, sq); }
    #pragma unroll
    for(int off = 32; off; off >>= 1) sq += __shfl_down(sq, off);
    if(t == 0){
        float var = sq / (float)GG;
        float rstd = rsqrtf(var + BN_EPS);
        float sc = rstd * gamma[j];
        scale_[j] = sc;
        shift_[j] = beta[j] - mean*sc;
    }
}

// ---------------- BN apply + fc1 + relu + fc2 + log_softmax ----------------
__global__ __launch_bounds__(128) void k_mlp(const float* __restrict__ outp, const float* __restrict__ scale_,
                     const float* __restrict__ shift_, const float* __restrict__ fc1w,
                     const float* __restrict__ fc1b, const float* __restrict__ fc2w,
                     const float* __restrict__ fc2b, float* __restrict__ out){
    __shared__ float nrm[F_OUT];
    __shared__ float hid[PENN];
    __shared__ float logit[CC];
    int r = blockIdx.x, t = threadIdx.x;
    for(int j = t; j < F_OUT; j += 128)
        nrm[j] = fmaf(outp[(size_t)r*F_OUT + j], scale_[j], shift_[j]);
    __syncthreads();
    float acc = fc1b[t];
    #pragma unroll 8
    for(int j = 0; j < F_OUT; ++j) acc = fmaf(nrm[j], fc1w[(size_t)t*F_OUT + j], acc);
    hid[t] = acc > 0.f ? acc : 0.f;
    __syncthreads();
    if(t < CC){
        float a = fc2b[t];
        #pragma unroll
        for(int p = 0; p < PENN; ++p) a = fmaf(hid[p], fc2w[t*PENN + p], a);
        logit[t] = a;
    }
    __syncthreads();
    if(t < CC){
        float m = logit[0];
        #pragma unroll
        for(int c = 1; c < CC; ++c) m = fmaxf(m, logit[c]);
        float se = 0.f;
        #pragma unroll
        for(int c = 0; c < CC; ++c) se += expf(logit[c] - m);
        out[r*CC + t] = logit[t] - m - logf(se);
    }
}

extern "C" void kernel_launch(void* const* d_in, const int* in_sizes, int n_in,
                              void* d_out, int out_size, void* d_ws, size_t ws_size,
                              hipStream_t stream){
    const float* x      = (const float*)d_in[0];
    const int*   edges  = (const int*)d_in[1];
    const int*   batch  = (const int*)d_in[2];
    const float* adjh   = (const float*)d_in[3];
    const float* fh     = (const float*)d_in[4];   // z0
    const float* fc_w   = (const float*)d_in[5];
    const float* fc_b   = (const float*)d_in[6];
    const float* rw_w   = (const float*)d_in[7];
    const float* rw_b   = (const float*)d_in[8];
    const float* gamma  = (const float*)d_in[9];
    const float* beta   = (const float*)d_in[10];
    const float* fc1w   = (const float*)d_in[11];
    const float* fc1b   = (const float*)d_in[12];
    const float* fc2w   = (const float*)d_in[13];
    const float* fc2b   = (const float*)d_in[14];
    float* out = (float*)d_out;

    const int* row = edges;
    const int* col = edges + E_EDGES;

    // workspace carve-up
    size_t off = 0;
    auto alloc_f = [&](size_t nf) -> float* {
        float* p = (float*)((char*)d_ws + off);
        off += nf * sizeof(float);
        off = (off + 255) & ~(size_t)255;
        return p;
    };
    float* deg    = alloc_f(N_NODES);
    float* xh     = alloc_f((size_t)N_NODES*DD);
    float* ybuf   = alloc_f((size_t)N_NODES*DD);
    float* agg1   = alloc_f((size_t)N_NODES*DD);
    float* agg2   = alloc_f((size_t)N_NODES*DD);
    float* cur1   = alloc_f((size_t)N_NODES*DD);
    float* cur2   = alloc_f((size_t)N_NODES*DD);
    float* z1     = alloc_f(HH*SS*DD);
    float* z2     = alloc_f(HH*SS*DD);
    float* P      = alloc_f((size_t)3*GG*HS);
    float* outp   = alloc_f((size_t)GG*F_OUT);
    float* scl    = alloc_f(F_OUT);
    float* shf    = alloc_f(F_OUT);
    int*   start  = (int*)alloc_f(GG + 1);
    int*   cnt    = (int*)alloc_f(N_NODES);
    int*   rowptr = (int*)alloc_f(N_NODES + 1);
    int*   cursor = (int*)alloc_f(N_NODES);
    int*   erow   = (int*)alloc_f(E_EDGES);

    int blkN = (N_NODES + 255)/256;
    int blkE = (E_EDGES + 255)/256;

    // degree + CSR build (edge-structure only; reused by both gathers)
    k_init_deg<<<blkN, 256, 0, stream>>>(deg);
    k_deg<<<blkE, 256, 0, stream>>>(row, deg);
    k_zero_cnt<<<blkN, 256, 0, stream>>>(cnt);
    k_hist<<<blkE, 256, 0, stream>>>(col, cnt);
    k_scan<<<1, 1024, 0, stream>>>(cnt, rowptr, cursor);
    k_fill<<<blkE, 256, 0, stream>>>(row, col, cursor, erow);

    k_xh<<<1024, 256, 0, stream>>>(x, fc_w, fc_b, deg, xh, ybuf);
    k_gather<<<1024, 256, 0, stream>>>(rowptr, erow, ybuf, agg1);
    k_lin<<<1024, 256, 0, stream>>>(agg1, rw_w, rw_b, deg, cur1, ybuf, 1);
    k_gather<<<1024, 256, 0, stream>>>(rowptr, erow, ybuf, agg2);
    k_lin<<<1024, 256, 0, stream>>>(agg2, rw_w + DD*DD, rw_b + DD, deg, cur2, nullptr, 0);

    k_z<<<1, 256, 0, stream>>>(adjh, fh, z1, z2);
    k_bounds<<<blkN, 256, 0, stream>>>(batch, start);
    k_feat3<<<2*GG, 192, 0, stream>>>(fh, z1, z2, xh, cur1, cur2, start, P);
    k_outpre<<<(GG*F_OUT + 255)/256, 256, 0, stream>>>(P, outp);
    k_bnstats<<<F_OUT, 64, 0, stream>>>(outp, gamma, beta, scl, shf);
    k_mlp<<<GG, 128, 0, stream>>>(outp, scl, shf, fc1w, fc1b, fc2w, fc2b, out);
}

// Round 11
// 1719.161 us; speedup vs baseline: 1.3180x; 1.3180x over previous
//
#include <hip/hip_runtime.h>
#include <stdint.h>

#define N_NODES 100000
#define E_EDGES 1600000
#define INDIM 128
#define DD 64
#define HH 16
#define SS 8
#define HS 128            // H*S
#define GG 512
#define PENN 128
#define CC 10
#define F_OUT 384
#define BN_EPS 1e-5f

// ---------------- degree (out-degree over row + self loop) ----------------
__global__ void k_init_deg(float* deg){
    int n = blockIdx.x*256 + threadIdx.x;
    if(n < N_NODES) deg[n] = 1.0f;   // self loop
}

__global__ void k_deg(const int* __restrict__ row, float* deg){
    int e = blockIdx.x*256 + threadIdx.x;
    if(e < E_EDGES) atomicAdd(&deg[row[e]], 1.0f);
}

// ---------------- CSR-by-col build (once per launch, reused by both gathers) ----------------
__global__ void k_zero_cnt(int* cnt){
    int n = blockIdx.x*256 + threadIdx.x;
    if(n < N_NODES) cnt[n] = 0;
}

__global__ void k_hist(const int* __restrict__ col, int* __restrict__ cnt){
    int e = blockIdx.x*256 + threadIdx.x;
    if(e < E_EDGES) atomicAdd(&cnt[col[e]], 1);
}

// single-block exclusive scan over cnt -> rowptr[0..N], cursor copy
__global__ __launch_bounds__(1024) void k_scan(const int* __restrict__ cnt,
                                               int* __restrict__ rowptr,
                                               int* __restrict__ cursor){
    __shared__ int buf[1024];
    __shared__ int carry;
    int t = threadIdx.x;
    if(t == 0) carry = 0;
    __syncthreads();
    for(int base = 0; base < N_NODES; base += 1024){
        int i = base + t;
        int v = (i < N_NODES) ? cnt[i] : 0;
        buf[t] = v;
        __syncthreads();
        for(int off = 1; off < 1024; off <<= 1){
            int add = (t >= off) ? buf[t - off] : 0;
            __syncthreads();
            buf[t] += add;
            __syncthreads();
        }
        int excl = buf[t] - v;
        int total = buf[1023];
        int base_c = carry;
        if(i < N_NODES){ rowptr[i] = base_c + excl; cursor[i] = base_c + excl; }
        __syncthreads();
        if(t == 0) carry = base_c + total;
        __syncthreads();
    }
    if(t == 0) rowptr[N_NODES] = carry;   // == E_EDGES
}

__global__ void k_fill(const int* __restrict__ row, const int* __restrict__ col,
                       int* __restrict__ cursor, int* __restrict__ erow){
    int e = blockIdx.x*256 + threadIdx.x;
    if(e < E_EDGES){
        int idx = atomicAdd(&cursor[col[e]], 1);
        erow[idx] = row[e];
    }
}

// ---------------- xh = sigmoid(x @ fc_w^T + b); y0 = xh/deg ----------------
// weights in registers: lane d holds fc_w[d][0..127]; x row read as wave-uniform float4 broadcasts.
__global__ __launch_bounds__(256) void k_xh(const float* __restrict__ x, const float* __restrict__ fc_w,
                     const float* __restrict__ fc_b, const float* __restrict__ deg,
                     float* __restrict__ xh, float* __restrict__ ybuf){
    int lane = threadIdx.x & 63;
    int wave = (blockIdx.x*256 + threadIdx.x) >> 6;
    int nwaves = gridDim.x * 4;
    float w[INDIM];
    const float4* wr = (const float4*)(fc_w + (size_t)lane*INDIM);
    #pragma unroll
    for(int q = 0; q < INDIM/4; ++q){
        float4 v = wr[q];
        w[4*q+0] = v.x; w[4*q+1] = v.y; w[4*q+2] = v.z; w[4*q+3] = v.w;
    }
    float bias = fc_b[lane];
    #pragma unroll 1
    for(int n = wave; n < N_NODES; n += nwaves){
        const float4* xr = (const float4*)(x + (size_t)n*INDIM);
        float acc = bias;
        #pragma unroll
        for(int q = 0; q < INDIM/4; ++q){
            float4 v = xr[q];
            acc = fmaf(v.x, w[4*q+0], acc);
            acc = fmaf(v.y, w[4*q+1], acc);
            acc = fmaf(v.z, w[4*q+2], acc);
            acc = fmaf(v.w, w[4*q+3], acc);
        }
        float s = 1.0f/(1.0f + expf(-acc));
        size_t o = (size_t)n*DD + lane;
        xh[o] = s;
        ybuf[o] = s / deg[n];
    }
}

// ---------------- gather-based aggregation: agg[n] = y[n] + sum_{e: col==n} y[row[e]] ----------------
// one wave per node, lane = d. No atomics; erow run order only permutes the FP sum.
__global__ __launch_bounds__(256) void k_gather(const int* __restrict__ rowptr, const int* __restrict__ erow,
                        const float* __restrict__ y, float* __restrict__ agg){
    int lane = threadIdx.x & 63;
    int wave = (blockIdx.x*256 + threadIdx.x) >> 6;
    int nwaves = gridDim.x * 4;
    #pragma unroll 1
    for(int n = wave; n < N_NODES; n += nwaves){
        int b = rowptr[n], en = rowptr[n+1];
        float acc = y[(size_t)n*DD + lane];    // self loop
        #pragma unroll 1
        for(int j = b; j < en; ++j){
            int rr = erow[j];
            acc += y[(size_t)rr*DD + lane];
        }
        agg[(size_t)n*DD + lane] = acc;
    }
}

// ---------------- cur = agg @ w^T + b ; optionally y_next = cur/deg ----------------
// weights in registers: lane d holds w[d][0..63]
__global__ __launch_bounds__(256) void k_lin(const float* __restrict__ agg, const float* __restrict__ w_,
                     const float* __restrict__ b, const float* __restrict__ deg,
                     float* __restrict__ cur, float* __restrict__ ynext, int make_next){
    int lane = threadIdx.x & 63;
    int wave = (blockIdx.x*256 + threadIdx.x) >> 6;
    int nwaves = gridDim.x * 4;
    float w[DD];
    const float4* wr = (const float4*)(w_ + (size_t)lane*DD);
    #pragma unroll
    for(int q = 0; q < DD/4; ++q){
        float4 v = wr[q];
        w[4*q+0] = v.x; w[4*q+1] = v.y; w[4*q+2] = v.z; w[4*q+3] = v.w;
    }
    float bias = b[lane];
    #pragma unroll 1
    for(int n = wave; n < N_NODES; n += nwaves){
        const float4* ar = (const float4*)(agg + (size_t)n*DD);
        float acc = bias;
        #pragma unroll
        for(int q = 0; q < DD/4; ++q){
            float4 v = ar[q];
            acc = fmaf(v.x, w[4*q+0], acc);
            acc = fmaf(v.y, w[4*q+1], acc);
            acc = fmaf(v.z, w[4*q+2], acc);
            acc = fmaf(v.w, w[4*q+3], acc);
        }
        size_t o = (size_t)n*DD + lane;
        cur[o] = acc;
        if(make_next) ynext[o] = acc / deg[n];
    }
}

// ---------------- z1 = A@z0, z2 = A@z1 (A from relu'd upper-tri params, symmetrized) ----------------
__global__ void k_z(const float* __restrict__ adj_hidden, const float* __restrict__ z0,
                    float* __restrict__ z1, float* __restrict__ z2){
    __shared__ float A[HH][SS][SS];
    __shared__ float zb[HH][SS][DD];
    int tid = threadIdx.x;
    for(int i = tid; i < HH*SS*SS; i += 256) ((float*)A)[i] = 0.0f;
    __syncthreads();
    for(int i = tid; i < HH*28; i += 256){
        int h = i / 28, p = i % 28;
        int iu = 0, ju = 0, cnt = 0;
        for(int a = 0; a < SS-1; ++a){
            int rl = SS-1-a;
            if(p < cnt + rl){ iu = a; ju = a + 1 + (p - cnt); break; }
            cnt += rl;
        }
        float v = adj_hidden[i];
        v = v > 0.f ? v : 0.f;
        A[h][iu][ju] = v;
        A[h][ju][iu] = v;
    }
    __syncthreads();
    for(int i = tid; i < HH*SS*DD; i += 256){
        int h = i >> 9, a = (i >> 6) & 7, d = i & 63;
        float acc = 0.f;
        #pragma unroll
        for(int bb = 0; bb < SS; ++bb) acc += A[h][a][bb] * z0[(h*SS+bb)*DD + d];
        z1[i] = acc;
        zb[h][a][d] = acc;
    }
    __syncthreads();
    for(int i = tid; i < HH*SS*DD; i += 256){
        int h = i >> 9, a = (i >> 6) & 7, d = i & 63;
        float acc = 0.f;
        #pragma unroll
        for(int bb = 0; bb < SS; ++bb) acc += A[h][a][bb] * zb[h][bb][d];
        z2[i] = acc;
    }
}

// ---------------- graph boundaries from sorted batch ----------------
__global__ void k_bounds(const int* __restrict__ batch, int* __restrict__ start){
    int n = blockIdx.x*256 + threadIdx.x;
    if(n >= N_NODES) return;
    int b = batch[n];
    int prev = (n == 0) ? -1 : batch[n-1];
    for(int g = prev + 1; g <= b; ++g) start[g] = n;
    if(n == N_NODES-1){
        for(int g = b + 1; g <= GG; ++g) start[g] = N_NODES;
    }
}

// ---------------- per-graph feature reduce, all 3 steps, no shuffles ----------------
// grid = GG blocks (one graph each); block = 256 threads = 128 hs x 2 node-slots.
// Per step: thread's z-row lives in REGISTERS (static indices only); 8-node cur
// chunks staged in LDS; dot = uniform-address LDS broadcast reads (conflict-free).
// Step 0 writes zx to zxbuf; steps 1,2 read it back (same thread wrote it).
__global__ __launch_bounds__(256) void k_feat(const float* __restrict__ z0, const float* __restrict__ z1,
                      const float* __restrict__ z2,
                      const float* __restrict__ xh, const float* __restrict__ cur1,
                      const float* __restrict__ cur2,
                      const int* __restrict__ start, float* __restrict__ P,
                      float* __restrict__ zxbuf){
    __shared__ float curl[8][DD];
    __shared__ float red[HS];
    int tid  = threadIdx.x;
    int hs   = tid & 127;
    int slot = tid >> 7;           // 0 or 1
    int g = blockIdx.x;
    int s0 = start[g], s1 = start[g+1];

    #pragma unroll 1
    for(int step = 0; step < 3; ++step){
        const float* z   = (step == 0) ? z0 : (step == 1 ? z1 : z2);
        const float* cur = (step == 0) ? xh : (step == 1 ? cur1 : cur2);

        // z row -> registers (fully static indexing; ~64 VGPR)
        float zr[DD];
        const float4* zp = (const float4*)(z + (size_t)hs*DD);
        #pragma unroll
        for(int q = 0; q < 16; ++q){
            float4 v = zp[q];
            zr[4*q+0] = v.x; zr[4*q+1] = v.y; zr[4*q+2] = v.z; zr[4*q+3] = v.w;
        }

        float acc = 0.f;
        #pragma unroll 1
        for(int base = s0; base < s1; base += 8){
            __syncthreads();                        // protect curl from prev iter reads
            for(int i = tid; i < 8*DD; i += 256){
                int nn = base + (i >> 6);
                curl[i >> 6][i & 63] = (nn < s1) ? cur[(size_t)nn*DD + (i & 63)] : 0.f;
            }
            __syncthreads();
            #pragma unroll
            for(int j = 0; j < 4; ++j){
                int n = base + slot*4 + j;
                if(n < s1){
                    const float4* cp = (const float4*)(curl[slot*4 + j]);
                    float dot = 0.f;
                    #pragma unroll
                    for(int q = 0; q < 16; ++q){
                        float4 v = cp[q];           // wave-uniform address -> broadcast
                        dot = fmaf(v.x, zr[4*q+0], dot);
                        dot = fmaf(v.y, zr[4*q+1], dot);
                        dot = fmaf(v.z, zr[4*q+2], dot);
                        dot = fmaf(v.w, zr[4*q+3], dot);
                    }
                    if(step == 0){
                        zxbuf[(size_t)n*HS + hs] = dot;       // coalesced
                        acc = fmaf(dot, dot, acc);
                    } else {
                        float zx = zxbuf[(size_t)n*HS + hs];  // own write from step 0
                        acc = fmaf(zx, dot, acc);
                    }
                }
            }
        }
        __syncthreads();
        if(slot == 1) red[hs] = acc;
        __syncthreads();
        if(slot == 0) P[((size_t)step*GG + g)*HS + hs] = acc + red[hs];
        __syncthreads();                            // red safe for next step
    }
}

// ---------------- scrambled reshape: out_pre[r][i*128+c] = P_i[g,h,s] ----------------
__global__ void k_outpre(const float* __restrict__ P, float* __restrict__ outp){
    int idx = blockIdx.x*256 + threadIdx.x;
    if(idx >= GG*F_OUT) return;
    int r = idx / F_OUT, j = idx % F_OUT;
    int i = j >> 7, c = j & 127;
    int g = ((r & 63) << 3) + (c >> 4);
    int h = c & 15, s = r >> 6;
    int hs = h*SS + s;
    outp[idx] = P[((size_t)i*GG + g)*HS + hs];
}

// ---------------- batchnorm stats per column (training-mode batch stats) ----------------
__global__ void k_bnstats(const float* __restrict__ outp, const float* __restrict__ gamma,
                          const float* __restrict__ beta, float* __restrict__ scale_,
                          float* __restrict__ shift_){
    int j = blockIdx.x;     // 384 columns
    int t = threadIdx.x;    // 64 threads
    float v[8];
    float sum = 0.f;
    #pragma unroll
    for(int i = 0; i < 8; ++i){ v[i] = outp[(size_t)(t*8+i)*F_OUT + j]; sum += v[i]; }
    #pragma unroll
    for(int off = 32; off; off >>= 1) sum += __shfl_down(sum, off);
    sum = __shfl(sum, 0);
    float mean = sum / (float)GG;
    float sq = 0.f;
    #pragma unroll
    for(int i = 0; i < 8; ++i){ float d = v[i] - mean; sq = fmaf(d, d, sq); }
    #pragma unroll
    for(int off = 32; off; off >>= 1) sq += __shfl_down(sq, off);
    if(t == 0){
        float var = sq / (float)GG;
        float rstd = rsqrtf(var + BN_EPS);
        float sc = rstd * gamma[j];
        scale_[j] = sc;
        shift_[j] = beta[j] - mean*sc;
    }
}

// ---------------- BN apply + fc1 + relu + fc2 + log_softmax ----------------
__global__ __launch_bounds__(128) void k_mlp(const float* __restrict__ outp, const float* __restrict__ scale_,
                     const float* __restrict__ shift_, const float* __restrict__ fc1w,
                     const float* __restrict__ fc1b, const float* __restrict__ fc2w,
                     const float* __restrict__ fc2b, float* __restrict__ out){
    __shared__ float nrm[F_OUT];
    __shared__ float hid[PENN];
    __shared__ float logit[CC];
    int r = blockIdx.x, t = threadIdx.x;
    for(int j = t; j < F_OUT; j += 128)
        nrm[j] = fmaf(outp[(size_t)r*F_OUT + j], scale_[j], shift_[j]);
    __syncthreads();
    float acc = fc1b[t];
    #pragma unroll 8
    for(int j = 0; j < F_OUT; ++j) acc = fmaf(nrm[j], fc1w[(size_t)t*F_OUT + j], acc);
    hid[t] = acc > 0.f ? acc : 0.f;
    __syncthreads();
    if(t < CC){
        float a = fc2b[t];
        #pragma unroll
        for(int p = 0; p < PENN; ++p) a = fmaf(hid[p], fc2w[t*PENN + p], a);
        logit[t] = a;
    }
    __syncthreads();
    if(t < CC){
        float m = logit[0];
        #pragma unroll
        for(int c = 1; c < CC; ++c) m = fmaxf(m, logit[c]);
        float se = 0.f;
        #pragma unroll
        for(int c = 0; c < CC; ++c) se += expf(logit[c] - m);
        out[r*CC + t] = logit[t] - m - logf(se);
    }
}

extern "C" void kernel_launch(void* const* d_in, const int* in_sizes, int n_in,
                              void* d_out, int out_size, void* d_ws, size_t ws_size,
                              hipStream_t stream){
    const float* x      = (const float*)d_in[0];
    const int*   edges  = (const int*)d_in[1];
    const int*   batch  = (const int*)d_in[2];
    const float* adjh   = (const float*)d_in[3];
    const float* fh     = (const float*)d_in[4];   // z0
    const float* fc_w   = (const float*)d_in[5];
    const float* fc_b   = (const float*)d_in[6];
    const float* rw_w   = (const float*)d_in[7];
    const float* rw_b   = (const float*)d_in[8];
    const float* gamma  = (const float*)d_in[9];
    const float* beta   = (const float*)d_in[10];
    const float* fc1w   = (const float*)d_in[11];
    const float* fc1b   = (const float*)d_in[12];
    const float* fc2w   = (const float*)d_in[13];
    const float* fc2b   = (const float*)d_in[14];
    float* out = (float*)d_out;

    const int* row = edges;
    const int* col = edges + E_EDGES;

    // workspace carve-up
    size_t off = 0;
    auto alloc_f = [&](size_t nf) -> float* {
        float* p = (float*)((char*)d_ws + off);
        off += nf * sizeof(float);
        off = (off + 255) & ~(size_t)255;
        return p;
    };
    float* deg    = alloc_f(N_NODES);
    float* xh     = alloc_f((size_t)N_NODES*DD);
    float* ybuf   = alloc_f((size_t)N_NODES*DD);
    float* agg1   = alloc_f((size_t)N_NODES*DD);
    float* agg2   = alloc_f((size_t)N_NODES*DD);
    float* cur1   = alloc_f((size_t)N_NODES*DD);
    float* cur2   = alloc_f((size_t)N_NODES*DD);
    float* zxbuf  = alloc_f((size_t)N_NODES*HS);
    float* z1     = alloc_f(HH*SS*DD);
    float* z2     = alloc_f(HH*SS*DD);
    float* P      = alloc_f((size_t)3*GG*HS);
    float* outp   = alloc_f((size_t)GG*F_OUT);
    float* scl    = alloc_f(F_OUT);
    float* shf    = alloc_f(F_OUT);
    int*   start  = (int*)alloc_f(GG + 1);
    int*   cnt    = (int*)alloc_f(N_NODES);
    int*   rowptr = (int*)alloc_f(N_NODES + 1);
    int*   cursor = (int*)alloc_f(N_NODES);
    int*   erow   = (int*)alloc_f(E_EDGES);

    int blkN = (N_NODES + 255)/256;
    int blkE = (E_EDGES + 255)/256;

    // degree + CSR build (edge-structure only; reused by both gathers)
    k_init_deg<<<blkN, 256, 0, stream>>>(deg);
    k_deg<<<blkE, 256, 0, stream>>>(row, deg);
    k_zero_cnt<<<blkN, 256, 0, stream>>>(cnt);
    k_hist<<<blkE, 256, 0, stream>>>(col, cnt);
    k_scan<<<1, 1024, 0, stream>>>(cnt, rowptr, cursor);
    k_fill<<<blkE, 256, 0, stream>>>(row, col, cursor, erow);

    k_xh<<<1024, 256, 0, stream>>>(x, fc_w, fc_b, deg, xh, ybuf);
    k_gather<<<1024, 256, 0, stream>>>(rowptr, erow, ybuf, agg1);
    k_lin<<<1024, 256, 0, stream>>>(agg1, rw_w, rw_b, deg, cur1, ybuf, 1);
    k_gather<<<1024, 256, 0, stream>>>(rowptr, erow, ybuf, agg2);
    k_lin<<<1024, 256, 0, stream>>>(agg2, rw_w + DD*DD, rw_b + DD, deg, cur2, nullptr, 0);

    k_z<<<1, 256, 0, stream>>>(adjh, fh, z1, z2);
    k_bounds<<<blkN, 256, 0, stream>>>(batch, start);
    k_feat<<<GG, 256, 0, stream>>>(fh, z1, z2, xh, cur1, cur2, start, P, zxbuf);
    k_outpre<<<(GG*F_OUT + 255)/256, 256, 0, stream>>>(P, outp);
    k_bnstats<<<F_OUT, 64, 0, stream>>>(outp, gamma, beta, scl, shf);
    k_mlp<<<GG, 128, 0, stream>>>(outp, scl, shf, fc1w, fc1b, fc2w, fc2b, out);
}

// Round 12
// 1539.490 us; speedup vs baseline: 1.4718x; 1.1167x over previous
//
#include <hip/hip_runtime.h>
#include <stdint.h>

#define N_NODES 100000
#define E_EDGES 1600000
#define INDIM 128
#define DD 64
#define HH 16
#define SS 8
#define HS 128            // H*S
#define GG 512
#define PENN 128
#define CC 10
#define F_OUT 384
#define BN_EPS 1e-5f

// ---------------- degree (out-degree over row + self loop) ----------------
__global__ void k_init_deg(float* deg){
    int n = blockIdx.x*256 + threadIdx.x;
    if(n < N_NODES) deg[n] = 1.0f;   // self loop
}

__global__ void k_deg(const int* __restrict__ row, float* deg){
    int e = blockIdx.x*256 + threadIdx.x;
    if(e < E_EDGES) atomicAdd(&deg[row[e]], 1.0f);
}

// ---------------- CSR-by-col build (once per launch, reused by both gathers) ----------------
__global__ void k_zero_cnt(int* cnt){
    int n = blockIdx.x*256 + threadIdx.x;
    if(n < N_NODES) cnt[n] = 0;
}

__global__ void k_hist(const int* __restrict__ col, int* __restrict__ cnt){
    int e = blockIdx.x*256 + threadIdx.x;
    if(e < E_EDGES) atomicAdd(&cnt[col[e]], 1);
}

// single-block exclusive scan over cnt -> rowptr[0..N], cursor copy
__global__ __launch_bounds__(1024) void k_scan(const int* __restrict__ cnt,
                                               int* __restrict__ rowptr,
                                               int* __restrict__ cursor){
    __shared__ int buf[1024];
    __shared__ int carry;
    int t = threadIdx.x;
    if(t == 0) carry = 0;
    __syncthreads();
    for(int base = 0; base < N_NODES; base += 1024){
        int i = base + t;
        int v = (i < N_NODES) ? cnt[i] : 0;
        buf[t] = v;
        __syncthreads();
        for(int off = 1; off < 1024; off <<= 1){
            int add = (t >= off) ? buf[t - off] : 0;
            __syncthreads();
            buf[t] += add;
            __syncthreads();
        }
        int excl = buf[t] - v;
        int total = buf[1023];
        int base_c = carry;
        if(i < N_NODES){ rowptr[i] = base_c + excl; cursor[i] = base_c + excl; }
        __syncthreads();
        if(t == 0) carry = base_c + total;
        __syncthreads();
    }
    if(t == 0) rowptr[N_NODES] = carry;   // == E_EDGES
}

__global__ void k_fill(const int* __restrict__ row, const int* __restrict__ col,
                       int* __restrict__ cursor, int* __restrict__ erow){
    int e = blockIdx.x*256 + threadIdx.x;
    if(e < E_EDGES){
        int idx = atomicAdd(&cursor[col[e]], 1);
        erow[idx] = row[e];
    }
}

// ---------------- xh = sigmoid(x @ fc_w^T + b); y0 = xh/deg ----------------
// weights in registers (lane d holds fc_w[d][:]); 8 x-rows staged in LDS per chunk
// via coalesced float4 loads; dot reads x as uniform-address LDS broadcast with
// 4 independent accumulators (breaks the FMA dependence chain).
__global__ __launch_bounds__(256) void k_xh(const float* __restrict__ x, const float* __restrict__ fc_w,
                     const float* __restrict__ fc_b, const float* __restrict__ deg,
                     float* __restrict__ xh, float* __restrict__ ybuf){
    __shared__ float xl[8][INDIM];      // 4 KB
    int tid  = threadIdx.x;
    int lane = tid & 63;
    int wv   = tid >> 6;                // wave 0..3
    float w[INDIM];
    const float4* wr = (const float4*)(fc_w + (size_t)lane*INDIM);
    #pragma unroll
    for(int q = 0; q < INDIM/4; ++q){
        float4 v = wr[q];
        w[4*q+0] = v.x; w[4*q+1] = v.y; w[4*q+2] = v.z; w[4*q+3] = v.w;
    }
    float bias = fc_b[lane];
    int r = tid >> 5, q0 = tid & 31;    // staging role: row r, quad q0
    #pragma unroll 1
    for(int base = blockIdx.x*8; base < N_NODES; base += gridDim.x*8){
        __syncthreads();                 // xl reads from prev chunk done
        int nn = base + r;
        float4 v = (nn < N_NODES) ? ((const float4*)(x + (size_t)nn*INDIM))[q0]
                                  : make_float4(0.f,0.f,0.f,0.f);
        ((float4*)xl[r])[q0] = v;
        __syncthreads();
        #pragma unroll
        for(int j = 0; j < 2; ++j){
            int n = base + wv*2 + j;
            if(n < N_NODES){
                const float4* cp = (const float4*)xl[wv*2 + j];
                float a0 = 0.f, a1 = 0.f, a2 = 0.f, a3 = 0.f;
                #pragma unroll
                for(int q = 0; q < INDIM/4; q += 4){
                    float4 v0 = cp[q], v1 = cp[q+1], v2 = cp[q+2], v3 = cp[q+3];
                    a0 = fmaf(v0.x, w[4*q+ 0], a0); a0 = fmaf(v0.y, w[4*q+ 1], a0);
                    a0 = fmaf(v0.z, w[4*q+ 2], a0); a0 = fmaf(v0.w, w[4*q+ 3], a0);
                    a1 = fmaf(v1.x, w[4*q+ 4], a1); a1 = fmaf(v1.y, w[4*q+ 5], a1);
                    a1 = fmaf(v1.z, w[4*q+ 6], a1); a1 = fmaf(v1.w, w[4*q+ 7], a1);
                    a2 = fmaf(v2.x, w[4*q+ 8], a2); a2 = fmaf(v2.y, w[4*q+ 9], a2);
                    a2 = fmaf(v2.z, w[4*q+10], a2); a2 = fmaf(v2.w, w[4*q+11], a2);
                    a3 = fmaf(v3.x, w[4*q+12], a3); a3 = fmaf(v3.y, w[4*q+13], a3);
                    a3 = fmaf(v3.z, w[4*q+14], a3); a3 = fmaf(v3.w, w[4*q+15], a3);
                }
                float acc = bias + ((a0 + a1) + (a2 + a3));
                float s = 1.0f/(1.0f + expf(-acc));
                size_t o = (size_t)n*DD + lane;
                xh[o] = s;
                ybuf[o] = s / deg[n];
            }
        }
    }
}

// ---------------- gather-based aggregation: agg[n] = y[n] + sum_{e: col==n} y[row[e]] ----------------
// one wave per node, lane = d. No atomics; erow run order only permutes the FP sum.
__global__ __launch_bounds__(256) void k_gather(const int* __restrict__ rowptr, const int* __restrict__ erow,
                        const float* __restrict__ y, float* __restrict__ agg){
    int lane = threadIdx.x & 63;
    int wave = (blockIdx.x*256 + threadIdx.x) >> 6;
    int nwaves = gridDim.x * 4;
    #pragma unroll 1
    for(int n = wave; n < N_NODES; n += nwaves){
        int b = rowptr[n], en = rowptr[n+1];
        float acc = y[(size_t)n*DD + lane];    // self loop
        #pragma unroll 1
        for(int j = b; j < en; ++j){
            int rr = erow[j];
            acc += y[(size_t)rr*DD + lane];
        }
        agg[(size_t)n*DD + lane] = acc;
    }
}

// ---------------- cur = agg @ w^T + b ; optionally y_next = cur/deg ----------------
// weights in registers: lane d holds w[d][0..63]
__global__ __launch_bounds__(256) void k_lin(const float* __restrict__ agg, const float* __restrict__ w_,
                     const float* __restrict__ b, const float* __restrict__ deg,
                     float* __restrict__ cur, float* __restrict__ ynext, int make_next){
    int lane = threadIdx.x & 63;
    int wave = (blockIdx.x*256 + threadIdx.x) >> 6;
    int nwaves = gridDim.x * 4;
    float w[DD];
    const float4* wr = (const float4*)(w_ + (size_t)lane*DD);
    #pragma unroll
    for(int q = 0; q < DD/4; ++q){
        float4 v = wr[q];
        w[4*q+0] = v.x; w[4*q+1] = v.y; w[4*q+2] = v.z; w[4*q+3] = v.w;
    }
    float bias = b[lane];
    #pragma unroll 1
    for(int n = wave; n < N_NODES; n += nwaves){
        const float4* ar = (const float4*)(agg + (size_t)n*DD);
        float acc = bias;
        #pragma unroll
        for(int q = 0; q < DD/4; ++q){
            float4 v = ar[q];
            acc = fmaf(v.x, w[4*q+0], acc);
            acc = fmaf(v.y, w[4*q+1], acc);
            acc = fmaf(v.z, w[4*q+2], acc);
            acc = fmaf(v.w, w[4*q+3], acc);
        }
        size_t o = (size_t)n*DD + lane;
        cur[o] = acc;
        if(make_next) ynext[o] = acc / deg[n];
    }
}

// ---------------- z1 = A@z0, z2 = A@z1 (A from relu'd upper-tri params, symmetrized) ----------------
__global__ void k_z(const float* __restrict__ adj_hidden, const float* __restrict__ z0,
                    float* __restrict__ z1, float* __restrict__ z2){
    __shared__ float A[HH][SS][SS];
    __shared__ float zb[HH][SS][DD];
    int tid = threadIdx.x;
    for(int i = tid; i < HH*SS*SS; i += 256) ((float*)A)[i] = 0.0f;
    __syncthreads();
    for(int i = tid; i < HH*28; i += 256){
        int h = i / 28, p = i % 28;
        int iu = 0, ju = 0, cnt = 0;
        for(int a = 0; a < SS-1; ++a){
            int rl = SS-1-a;
            if(p < cnt + rl){ iu = a; ju = a + 1 + (p - cnt); break; }
            cnt += rl;
        }
        float v = adj_hidden[i];
        v = v > 0.f ? v : 0.f;
        A[h][iu][ju] = v;
        A[h][ju][iu] = v;
    }
    __syncthreads();
    for(int i = tid; i < HH*SS*DD; i += 256){
        int h = i >> 9, a = (i >> 6) & 7, d = i & 63;
        float acc = 0.f;
        #pragma unroll
        for(int bb = 0; bb < SS; ++bb) acc += A[h][a][bb] * z0[(h*SS+bb)*DD + d];
        z1[i] = acc;
        zb[h][a][d] = acc;
    }
    __syncthreads();
    for(int i = tid; i < HH*SS*DD; i += 256){
        int h = i >> 9, a = (i >> 6) & 7, d = i & 63;
        float acc = 0.f;
        #pragma unroll
        for(int bb = 0; bb < SS; ++bb) acc += A[h][a][bb] * zb[h][bb][d];
        z2[i] = acc;
    }
}

// ---------------- graph boundaries from sorted batch ----------------
__global__ void k_bounds(const int* __restrict__ batch, int* __restrict__ start){
    int n = blockIdx.x*256 + threadIdx.x;
    if(n >= N_NODES) return;
    int b = batch[n];
    int prev = (n == 0) ? -1 : batch[n-1];
    for(int g = prev + 1; g <= b; ++g) start[g] = n;
    if(n == N_NODES-1){
        for(int g = b + 1; g <= GG; ++g) start[g] = N_NODES;
    }
}

// ---------------- per-graph feature reduce, all 3 steps, no shuffles ----------------
// grid = GG blocks (one graph each); block = 256 threads = 128 hs x 2 node-slots.
// Per step: thread's z-row lives in REGISTERS (static indices only); 8-node cur
// chunks staged in LDS; dot = uniform-address LDS broadcast reads (conflict-free).
// Step 0 writes zx to zxbuf; steps 1,2 read it back (same thread wrote it).
__global__ __launch_bounds__(256) void k_feat(const float* __restrict__ z0, const float* __restrict__ z1,
                      const float* __restrict__ z2,
                      const float* __restrict__ xh, const float* __restrict__ cur1,
                      const float* __restrict__ cur2,
                      const int* __restrict__ start, float* __restrict__ P,
                      float* __restrict__ zxbuf){
    __shared__ float curl[8][DD];
    __shared__ float red[HS];
    int tid  = threadIdx.x;
    int hs   = tid & 127;
    int slot = tid >> 7;           // 0 or 1
    int g = blockIdx.x;
    int s0 = start[g], s1 = start[g+1];

    #pragma unroll 1
    for(int step = 0; step < 3; ++step){
        const float* z   = (step == 0) ? z0 : (step == 1 ? z1 : z2);
        const float* cur = (step == 0) ? xh : (step == 1 ? cur1 : cur2);

        // z row -> registers (fully static indexing; ~64 VGPR)
        float zr[DD];
        const float4* zp = (const float4*)(z + (size_t)hs*DD);
        #pragma unroll
        for(int q = 0; q < 16; ++q){
            float4 v = zp[q];
            zr[4*q+0] = v.x; zr[4*q+1] = v.y; zr[4*q+2] = v.z; zr[4*q+3] = v.w;
        }

        float acc = 0.f;
        #pragma unroll 1
        for(int base = s0; base < s1; base += 8){
            __syncthreads();                        // protect curl from prev iter reads
            for(int i = tid; i < 8*DD; i += 256){
                int nn = base + (i >> 6);
                curl[i >> 6][i & 63] = (nn < s1) ? cur[(size_t)nn*DD + (i & 63)] : 0.f;
            }
            __syncthreads();
            #pragma unroll
            for(int j = 0; j < 4; ++j){
                int n = base + slot*4 + j;
                if(n < s1){
                    const float4* cp = (const float4*)(curl[slot*4 + j]);
                    float dot = 0.f;
                    #pragma unroll
                    for(int q = 0; q < 16; ++q){
                        float4 v = cp[q];           // wave-uniform address -> broadcast
                        dot = fmaf(v.x, zr[4*q+0], dot);
                        dot = fmaf(v.y, zr[4*q+1], dot);
                        dot = fmaf(v.z, zr[4*q+2], dot);
                        dot = fmaf(v.w, zr[4*q+3], dot);
                    }
                    if(step == 0){
                        zxbuf[(size_t)n*HS + hs] = dot;       // coalesced
                        acc = fmaf(dot, dot, acc);
                    } else {
                        float zx = zxbuf[(size_t)n*HS + hs];  // own write from step 0
                        acc = fmaf(zx, dot, acc);
                    }
                }
            }
        }
        __syncthreads();
        if(slot == 1) red[hs] = acc;
        __syncthreads();
        if(slot == 0) P[((size_t)step*GG + g)*HS + hs] = acc + red[hs];
        __syncthreads();                            // red safe for next step
    }
}

// ---------------- scrambled reshape: out_pre[r][i*128+c] = P_i[g,h,s] ----------------
__global__ void k_outpre(const float* __restrict__ P, float* __restrict__ outp){
    int idx = blockIdx.x*256 + threadIdx.x;
    if(idx >= GG*F_OUT) return;
    int r = idx / F_OUT, j = idx % F_OUT;
    int i = j >> 7, c = j & 127;
    int g = ((r & 63) << 3) + (c >> 4);
    int h = c & 15, s = r >> 6;
    int hs = h*SS + s;
    outp[idx] = P[((size_t)i*GG + g)*HS + hs];
}

// ---------------- batchnorm stats per column (training-mode batch stats) ----------------
__global__ void k_bnstats(const float* __restrict__ outp, const float* __restrict__ gamma,
                          const float* __restrict__ beta, float* __restrict__ scale_,
                          float* __restrict__ shift_){
    int j = blockIdx.x;     // 384 columns
    int t = threadIdx.x;    // 64 threads
    float v[8];
    float sum = 0.f;
    #pragma unroll
    for(int i = 0; i < 8; ++i){ v[i] = outp[(size_t)(t*8+i)*F_OUT + j]; sum += v[i]; }
    #pragma unroll
    for(int off = 32; off; off >>= 1) sum += __shfl_down(sum, off);
    sum = __shfl(sum, 0);
    float mean = sum / (float)GG;
    float sq = 0.f;
    #pragma unroll
    for(int i = 0; i < 8; ++i){ float d = v[i] - mean; sq = fmaf(d, d, sq); }
    #pragma unroll
    for(int off = 32; off; off >>= 1) sq += __shfl_down(sq, off);
    if(t == 0){
        float var = sq / (float)GG;
        float rstd = rsqrtf(var + BN_EPS);
        float sc = rstd * gamma[j];
        scale_[j] = sc;
        shift_[j] = beta[j] - mean*sc;
    }
}

// ---------------- BN apply + fc1 + relu + fc2 + log_softmax ----------------
__global__ __launch_bounds__(128) void k_mlp(const float* __restrict__ outp, const float* __restrict__ scale_,
                     const float* __restrict__ shift_, const float* __restrict__ fc1w,
                     const float* __restrict__ fc1b, const float* __restrict__ fc2w,
                     const float* __restrict__ fc2b, float* __restrict__ out){
    __shared__ float nrm[F_OUT];
    __shared__ float hid[PENN];
    __shared__ float logit[CC];
    int r = blockIdx.x, t = threadIdx.x;
    for(int j = t; j < F_OUT; j += 128)
        nrm[j] = fmaf(outp[(size_t)r*F_OUT + j], scale_[j], shift_[j]);
    __syncthreads();
    float acc = fc1b[t];
    #pragma unroll 8
    for(int j = 0; j < F_OUT; ++j) acc = fmaf(nrm[j], fc1w[(size_t)t*F_OUT + j], acc);
    hid[t] = acc > 0.f ? acc : 0.f;
    __syncthreads();
    if(t < CC){
        float a = fc2b[t];
        #pragma unroll
        for(int p = 0; p < PENN; ++p) a = fmaf(hid[p], fc2w[t*PENN + p], a);
        logit[t] = a;
    }
    __syncthreads();
    if(t < CC){
        float m = logit[0];
        #pragma unroll
        for(int c = 1; c < CC; ++c) m = fmaxf(m, logit[c]);
        float se = 0.f;
        #pragma unroll
        for(int c = 0; c < CC; ++c) se += expf(logit[c] - m);
        out[r*CC + t] = logit[t] - m - logf(se);
    }
}

extern "C" void kernel_launch(void* const* d_in, const int* in_sizes, int n_in,
                              void* d_out, int out_size, void* d_ws, size_t ws_size,
                              hipStream_t stream){
    const float* x      = (const float*)d_in[0];
    const int*   edges  = (const int*)d_in[1];
    const int*   batch  = (const int*)d_in[2];
    const float* adjh   = (const float*)d_in[3];
    const float* fh     = (const float*)d_in[4];   // z0
    const float* fc_w   = (const float*)d_in[5];
    const float* fc_b   = (const float*)d_in[6];
    const float* rw_w   = (const float*)d_in[7];
    const float* rw_b   = (const float*)d_in[8];
    const float* gamma  = (const float*)d_in[9];
    const float* beta   = (const float*)d_in[10];
    const float* fc1w   = (const float*)d_in[11];
    const float* fc1b   = (const float*)d_in[12];
    const float* fc2w   = (const float*)d_in[13];
    const float* fc2b   = (const float*)d_in[14];
    float* out = (float*)d_out;

    const int* row = edges;
    const int* col = edges + E_EDGES;

    // workspace carve-up
    size_t off = 0;
    auto alloc_f = [&](size_t nf) -> float* {
        float* p = (float*)((char*)d_ws + off);
        off += nf * sizeof(float);
        off = (off + 255) & ~(size_t)255;
        return p;
    };
    float* deg    = alloc_f(N_NODES);
    float* xh     = alloc_f((size_t)N_NODES*DD);
    float* ybuf   = alloc_f((size_t)N_NODES*DD);
    float* agg1   = alloc_f((size_t)N_NODES*DD);
    float* agg2   = alloc_f((size_t)N_NODES*DD);
    float* cur1   = alloc_f((size_t)N_NODES*DD);
    float* cur2   = alloc_f((size_t)N_NODES*DD);
    float* zxbuf  = alloc_f((size_t)N_NODES*HS);
    float* z1     = alloc_f(HH*SS*DD);
    float* z2     = alloc_f(HH*SS*DD);
    float* P      = alloc_f((size_t)3*GG*HS);
    float* outp   = alloc_f((size_t)GG*F_OUT);
    float* scl    = alloc_f(F_OUT);
    float* shf    = alloc_f(F_OUT);
    int*   start  = (int*)alloc_f(GG + 1);
    int*   cnt    = (int*)alloc_f(N_NODES);
    int*   rowptr = (int*)alloc_f(N_NODES + 1);
    int*   cursor = (int*)alloc_f(N_NODES);
    int*   erow   = (int*)alloc_f(E_EDGES);

    int blkN = (N_NODES + 255)/256;
    int blkE = (E_EDGES + 255)/256;

    // degree + CSR build (edge-structure only; reused by both gathers)
    k_init_deg<<<blkN, 256, 0, stream>>>(deg);
    k_deg<<<blkE, 256, 0, stream>>>(row, deg);
    k_zero_cnt<<<blkN, 256, 0, stream>>>(cnt);
    k_hist<<<blkE, 256, 0, stream>>>(col, cnt);
    k_scan<<<1, 1024, 0, stream>>>(cnt, rowptr, cursor);
    k_fill<<<blkE, 256, 0, stream>>>(row, col, cursor, erow);

    k_xh<<<1024, 256, 0, stream>>>(x, fc_w, fc_b, deg, xh, ybuf);
    k_gather<<<1024, 256, 0, stream>>>(rowptr, erow, ybuf, agg1);
    k_lin<<<1024, 256, 0, stream>>>(agg1, rw_w, rw_b, deg, cur1, ybuf, 1);
    k_gather<<<1024, 256, 0, stream>>>(rowptr, erow, ybuf, agg2);
    k_lin<<<1024, 256, 0, stream>>>(agg2, rw_w + DD*DD, rw_b + DD, deg, cur2, nullptr, 0);

    k_z<<<1, 256, 0, stream>>>(adjh, fh, z1, z2);
    k_bounds<<<blkN, 256, 0, stream>>>(batch, start);
    k_feat<<<GG, 256, 0, stream>>>(fh, z1, z2, xh, cur1, cur2, start, P, zxbuf);
    k_outpre<<<(GG*F_OUT + 255)/256, 256, 0, stream>>>(P, outp);
    k_bnstats<<<F_OUT, 64, 0, stream>>>(outp, gamma, beta, scl, shf);
    k_mlp<<<GG, 128, 0, stream>>>(outp, scl, shf, fc1w, fc1b, fc2w, fc2b, out);
}

// Round 13
// 1350.711 us; speedup vs baseline: 1.6775x; 1.1398x over previous
//
#include <hip/hip_runtime.h>
#include <stdint.h>

#define N_NODES 100000
#define E_EDGES 1600000
#define INDIM 128
#define DD 64
#define HH 16
#define SS 8
#define HS 128            // H*S
#define GG 512
#define PENN 128
#define CC 10
#define F_OUT 384
#define BN_EPS 1e-5f
#define NBLK_SCAN ((N_NODES + 255)/256)   // 391

// ---------------- degree (out-degree over row + self loop) ----------------
__global__ void k_init_deg(float* deg){
    int n = blockIdx.x*256 + threadIdx.x;
    if(n < N_NODES) deg[n] = 1.0f;   // self loop
}

__global__ void k_deg(const int* __restrict__ row, float* deg){
    int e = blockIdx.x*256 + threadIdx.x;
    if(e < E_EDGES) atomicAdd(&deg[row[e]], 1.0f);
}

// ---------------- CSR-by-col build (once per launch, reused by both gathers) ----------------
__global__ void k_zero_cnt(int* cnt){
    int n = blockIdx.x*256 + threadIdx.x;
    if(n < N_NODES) cnt[n] = 0;
}

__global__ void k_hist(const int* __restrict__ col, int* __restrict__ cnt){
    int e = blockIdx.x*256 + threadIdx.x;
    if(e < E_EDGES) atomicAdd(&cnt[col[e]], 1);
}

// two-level exclusive scan: (A) per-block sums, (B) scan of block sums, (C) local scan + offset
__global__ void k_scan_bsum(const int* __restrict__ cnt, int* __restrict__ bsum){
    int b = blockIdx.x, t = threadIdx.x, i = b*256 + t;
    int v = (i < N_NODES) ? cnt[i] : 0;
    #pragma unroll
    for(int off = 32; off; off >>= 1) v += __shfl_down(v, off);
    __shared__ int ws[4];
    if((t & 63) == 0) ws[t >> 6] = v;
    __syncthreads();
    if(t == 0) bsum[b] = ws[0] + ws[1] + ws[2] + ws[3];
}

__global__ __launch_bounds__(512) void k_scan_boff(const int* __restrict__ bsum,
                                                   int* __restrict__ boff,
                                                   int* __restrict__ rowptr){
    __shared__ int buf[512];
    int t = threadIdx.x;
    int v = (t < NBLK_SCAN) ? bsum[t] : 0;
    buf[t] = v;
    __syncthreads();
    for(int off = 1; off < 512; off <<= 1){
        int add = (t >= off) ? buf[t - off] : 0;
        __syncthreads();
        buf[t] += add;
        __syncthreads();
    }
    if(t < NBLK_SCAN) boff[t] = buf[t] - v;
    if(t == 0) rowptr[N_NODES] = buf[511];   // == E_EDGES
}

__global__ void k_scan_final(const int* __restrict__ cnt, const int* __restrict__ boff,
                             int* __restrict__ rowptr, int* __restrict__ cursor){
    int b = blockIdx.x, t = threadIdx.x, i = b*256 + t;
    int lane = t & 63, w = t >> 6;
    int v = (i < N_NODES) ? cnt[i] : 0;
    int x = v;
    #pragma unroll
    for(int off = 1; off < 64; off <<= 1){
        int y = __shfl_up(x, off);
        if(lane >= off) x += y;
    }
    __shared__ int wsum[4];
    if(lane == 63) wsum[w] = x;
    __syncthreads();
    int wpre = 0;
    #pragma unroll
    for(int k = 0; k < 4; ++k) wpre += (k < w) ? wsum[k] : 0;
    int excl = boff[b] + wpre + x - v;
    if(i < N_NODES){ rowptr[i] = excl; cursor[i] = excl; }
}

__global__ void k_fill(const int* __restrict__ row, const int* __restrict__ col,
                       int* __restrict__ cursor, int* __restrict__ erow){
    int e = blockIdx.x*256 + threadIdx.x;
    if(e < E_EDGES){
        int idx = atomicAdd(&cursor[col[e]], 1);
        erow[idx] = row[e];
    }
}

// ---------------- xh = sigmoid(x @ fc_w^T + b); y0 = xh/deg ----------------
// weights in registers; 8 x-rows staged in LDS; 4 independent accumulators.
__global__ __launch_bounds__(256) void k_xh(const float* __restrict__ x, const float* __restrict__ fc_w,
                     const float* __restrict__ fc_b, const float* __restrict__ deg,
                     float* __restrict__ xh, float* __restrict__ ybuf){
    __shared__ float xl[8][INDIM];      // 4 KB
    int tid  = threadIdx.x;
    int lane = tid & 63;
    int wv   = tid >> 6;                // wave 0..3
    float w[INDIM];
    const float4* wr = (const float4*)(fc_w + (size_t)lane*INDIM);
    #pragma unroll
    for(int q = 0; q < INDIM/4; ++q){
        float4 v = wr[q];
        w[4*q+0] = v.x; w[4*q+1] = v.y; w[4*q+2] = v.z; w[4*q+3] = v.w;
    }
    float bias = fc_b[lane];
    int r = tid >> 5, q0 = tid & 31;    // staging role: row r, quad q0
    #pragma unroll 1
    for(int base = blockIdx.x*8; base < N_NODES; base += gridDim.x*8){
        __syncthreads();
        int nn = base + r;
        float4 v = (nn < N_NODES) ? ((const float4*)(x + (size_t)nn*INDIM))[q0]
                                  : make_float4(0.f,0.f,0.f,0.f);
        ((float4*)xl[r])[q0] = v;
        __syncthreads();
        #pragma unroll
        for(int j = 0; j < 2; ++j){
            int n = base + wv*2 + j;
            if(n < N_NODES){
                const float4* cp = (const float4*)xl[wv*2 + j];
                float a0 = 0.f, a1 = 0.f, a2 = 0.f, a3 = 0.f;
                #pragma unroll
                for(int q = 0; q < INDIM/4; q += 4){
                    float4 v0 = cp[q], v1 = cp[q+1], v2 = cp[q+2], v3 = cp[q+3];
                    a0 = fmaf(v0.x, w[4*q+ 0], a0); a0 = fmaf(v0.y, w[4*q+ 1], a0);
                    a0 = fmaf(v0.z, w[4*q+ 2], a0); a0 = fmaf(v0.w, w[4*q+ 3], a0);
                    a1 = fmaf(v1.x, w[4*q+ 4], a1); a1 = fmaf(v1.y, w[4*q+ 5], a1);
                    a1 = fmaf(v1.z, w[4*q+ 6], a1); a1 = fmaf(v1.w, w[4*q+ 7], a1);
                    a2 = fmaf(v2.x, w[4*q+ 8], a2); a2 = fmaf(v2.y, w[4*q+ 9], a2);
                    a2 = fmaf(v2.z, w[4*q+10], a2); a2 = fmaf(v2.w, w[4*q+11], a2);
                    a3 = fmaf(v3.x, w[4*q+12], a3); a3 = fmaf(v3.y, w[4*q+13], a3);
                    a3 = fmaf(v3.z, w[4*q+14], a3); a3 = fmaf(v3.w, w[4*q+15], a3);
                }
                float acc = bias + ((a0 + a1) + (a2 + a3));
                float s = 1.0f/(1.0f + expf(-acc));
                size_t o = (size_t)n*DD + lane;
                xh[o] = s;
                ybuf[o] = s / deg[n];
            }
        }
    }
}

// ---------------- gather-based aggregation: agg[n] = y[n] + sum_{e: col==n} y[row[e]] ----------------
__global__ __launch_bounds__(256) void k_gather(const int* __restrict__ rowptr, const int* __restrict__ erow,
                        const float* __restrict__ y, float* __restrict__ agg){
    int lane = threadIdx.x & 63;
    int wave = (blockIdx.x*256 + threadIdx.x) >> 6;
    int nwaves = gridDim.x * 4;
    #pragma unroll 1
    for(int n = wave; n < N_NODES; n += nwaves){
        int b = rowptr[n], en = rowptr[n+1];
        float acc = y[(size_t)n*DD + lane];    // self loop
        #pragma unroll 1
        for(int j = b; j < en; ++j){
            int rr = erow[j];
            acc += y[(size_t)rr*DD + lane];
        }
        agg[(size_t)n*DD + lane] = acc;
    }
}

// ---------------- cur = agg @ w^T + b ; optionally y_next = cur/deg ----------------
__global__ __launch_bounds__(256) void k_lin(const float* __restrict__ agg, const float* __restrict__ w_,
                     const float* __restrict__ b, const float* __restrict__ deg,
                     float* __restrict__ cur, float* __restrict__ ynext, int make_next){
    int lane = threadIdx.x & 63;
    int wave = (blockIdx.x*256 + threadIdx.x) >> 6;
    int nwaves = gridDim.x * 4;
    float w[DD];
    const float4* wr = (const float4*)(w_ + (size_t)lane*DD);
    #pragma unroll
    for(int q = 0; q < DD/4; ++q){
        float4 v = wr[q];
        w[4*q+0] = v.x; w[4*q+1] = v.y; w[4*q+2] = v.z; w[4*q+3] = v.w;
    }
    float bias = b[lane];
    #pragma unroll 1
    for(int n = wave; n < N_NODES; n += nwaves){
        const float4* ar = (const float4*)(agg + (size_t)n*DD);
        float acc = bias;
        #pragma unroll
        for(int q = 0; q < DD/4; ++q){
            float4 v = ar[q];
            acc = fmaf(v.x, w[4*q+0], acc);
            acc = fmaf(v.y, w[4*q+1], acc);
            acc = fmaf(v.z, w[4*q+2], acc);
            acc = fmaf(v.w, w[4*q+3], acc);
        }
        size_t o = (size_t)n*DD + lane;
        cur[o] = acc;
        if(make_next) ynext[o] = acc / deg[n];
    }
}

// ---------------- z1 = A@z0, z2 = A@z1 ----------------
__global__ void k_z(const float* __restrict__ adj_hidden, const float* __restrict__ z0,
                    float* __restrict__ z1, float* __restrict__ z2){
    __shared__ float A[HH][SS][SS];
    __shared__ float zb[HH][SS][DD];
    int tid = threadIdx.x;
    for(int i = tid; i < HH*SS*SS; i += 256) ((float*)A)[i] = 0.0f;
    __syncthreads();
    for(int i = tid; i < HH*28; i += 256){
        int h = i / 28, p = i % 28;
        int iu = 0, ju = 0, cnt = 0;
        for(int a = 0; a < SS-1; ++a){
            int rl = SS-1-a;
            if(p < cnt + rl){ iu = a; ju = a + 1 + (p - cnt); break; }
            cnt += rl;
        }
        float v = adj_hidden[i];
        v = v > 0.f ? v : 0.f;
        A[h][iu][ju] = v;
        A[h][ju][iu] = v;
    }
    __syncthreads();
    for(int i = tid; i < HH*SS*DD; i += 256){
        int h = i >> 9, a = (i >> 6) & 7, d = i & 63;
        float acc = 0.f;
        #pragma unroll
        for(int bb = 0; bb < SS; ++bb) acc += A[h][a][bb] * z0[(h*SS+bb)*DD + d];
        z1[i] = acc;
        zb[h][a][d] = acc;
    }
    __syncthreads();
    for(int i = tid; i < HH*SS*DD; i += 256){
        int h = i >> 9, a = (i >> 6) & 7, d = i & 63;
        float acc = 0.f;
        #pragma unroll
        for(int bb = 0; bb < SS; ++bb) acc += A[h][a][bb] * zb[h][bb][d];
        z2[i] = acc;
    }
}

// ---------------- graph boundaries from sorted batch ----------------
__global__ void k_bounds(const int* __restrict__ batch, int* __restrict__ start){
    int n = blockIdx.x*256 + threadIdx.x;
    if(n >= N_NODES) return;
    int b = batch[n];
    int prev = (n == 0) ? -1 : batch[n-1];
    for(int g = prev + 1; g <= b; ++g) start[g] = n;
    if(n == N_NODES-1){
        for(int g = b + 1; g <= GG; ++g) start[g] = N_NODES;
    }
}

// ---------------- per-(graph,step) feature reduce; zx recomputed, no zxbuf ----------------
// grid = 3*GG blocks; block = 256 threads = 128 hs x 2 node-slots.
// P_i[g][hs] = sum_n (z0[hs]·xh[n]) * (z_i[hs]·cur_i[n]).  For i=0, cur=xh, z_i=z0.
// Both z rows in registers (static idx); xh+cur chunks staged in LDS; dot via
// uniform-address LDS broadcast; two independent FMA chains (zx, dot).
__global__ __launch_bounds__(256) void k_feat(const float* __restrict__ z0, const float* __restrict__ z1,
                      const float* __restrict__ z2,
                      const float* __restrict__ xh, const float* __restrict__ cur1,
                      const float* __restrict__ cur2,
                      const int* __restrict__ start, float* __restrict__ P){
    __shared__ float xhl[8][DD];
    __shared__ float curl[8][DD];
    __shared__ float red[HS];
    int tid  = threadIdx.x;
    int hs   = tid & 127;
    int slot = tid >> 7;           // 0 or 1
    int bid  = blockIdx.x;
    int g    = bid / 3;
    int i    = bid - g*3;          // step 0..2
    int s0 = start[g], s1 = start[g+1];

    const float* zi  = (i == 0) ? z0 : (i == 1 ? z1 : z2);
    const float* cur = (i == 0) ? xh : (i == 1 ? cur1 : cur2);

    // both z rows -> registers (static indexing)
    float z0r[DD], zir[DD];
    {
        const float4* p0 = (const float4*)(z0 + (size_t)hs*DD);
        const float4* pi = (const float4*)(zi + (size_t)hs*DD);
        #pragma unroll
        for(int q = 0; q < 16; ++q){
            float4 a = p0[q], b = pi[q];
            z0r[4*q+0]=a.x; z0r[4*q+1]=a.y; z0r[4*q+2]=a.z; z0r[4*q+3]=a.w;
            zir[4*q+0]=b.x; zir[4*q+1]=b.y; zir[4*q+2]=b.z; zir[4*q+3]=b.w;
        }
    }

    float acc = 0.f;
    #pragma unroll 1
    for(int base = s0; base < s1; base += 8){
        __syncthreads();                        // protect LDS from prev iter reads
        #pragma unroll
        for(int k = 0; k < 2; ++k){
            int idx = tid + k*256;              // 0..511
            int nn = base + (idx >> 6);
            int d  = idx & 63;
            bool ok = nn < s1;
            xhl [idx >> 6][d] = ok ? xh [(size_t)nn*DD + d] : 0.f;
            curl[idx >> 6][d] = ok ? cur[(size_t)nn*DD + d] : 0.f;
        }
        __syncthreads();
        #pragma unroll
        for(int j = 0; j < 4; ++j){
            int n = base + slot*4 + j;
            if(n < s1){
                const float4* xp = (const float4*)(xhl [slot*4 + j]);
                const float4* cp = (const float4*)(curl[slot*4 + j]);
                float zx = 0.f, dt = 0.f;       // two independent chains
                #pragma unroll
                for(int q = 0; q < 16; ++q){
                    float4 a = xp[q], b = cp[q];    // uniform-address -> broadcast
                    zx = fmaf(a.x, z0r[4*q+0], zx);
                    zx = fmaf(a.y, z0r[4*q+1], zx);
                    zx = fmaf(a.z, z0r[4*q+2], zx);
                    zx = fmaf(a.w, z0r[4*q+3], zx);
                    dt = fmaf(b.x, zir[4*q+0], dt);
                    dt = fmaf(b.y, zir[4*q+1], dt);
                    dt = fmaf(b.z, zir[4*q+2], dt);
                    dt = fmaf(b.w, zir[4*q+3], dt);
                }
                acc = fmaf(zx, dt, acc);
            }
        }
    }
    __syncthreads();
    if(slot == 1) red[hs] = acc;
    __syncthreads();
    if(slot == 0) P[((size_t)i*GG + g)*HS + hs] = acc + red[hs];
}

// ---------------- scrambled reshape: out_pre[r][i*128+c] = P_i[g,h,s] ----------------
__global__ void k_outpre(const float* __restrict__ P, float* __restrict__ outp){
    int idx = blockIdx.x*256 + threadIdx.x;
    if(idx >= GG*F_OUT) return;
    int r = idx / F_OUT, j = idx % F_OUT;
    int i = j >> 7, c = j & 127;
    int g = ((r & 63) << 3) + (c >> 4);
    int h = c & 15, s = r >> 6;
    int hs = h*SS + s;
    outp[idx] = P[((size_t)i*GG + g)*HS + hs];
}

// ---------------- batchnorm stats per column ----------------
__global__ void k_bnstats(const float* __restrict__ outp, const float* __restrict__ gamma,
                          const float* __restrict__ beta, float* __restrict__ scale_,
                          float* __restrict__ shift_){
    int j = blockIdx.x;     // 384 columns
    int t = threadIdx.x;    // 64 threads
    float v[8];
    float sum = 0.f;
    #pragma unroll
    for(int i = 0; i < 8; ++i){ v[i] = outp[(size_t)(t*8+i)*F_OUT + j]; sum += v[i]; }
    #pragma unroll
    for(int off = 32; off; off >>= 1) sum += __shfl_down(sum, off);
    sum = __shfl(sum, 0);
    float mean = sum / (float)GG;
    float sq = 0.f;
    #pragma unroll
    for(int i = 0; i < 8; ++i){ float d = v[i] - mean; sq = fmaf(d, d, sq); }
    #pragma unroll
    for(int off = 32; off; off >>= 1) sq += __shfl_down(sq, off);
    if(t == 0){
        float var = sq / (float)GG;
        float rstd = rsqrtf(var + BN_EPS);
        float sc = rstd * gamma[j];
        scale_[j] = sc;
        shift_[j] = beta[j] - mean*sc;
    }
}

// ---------------- BN apply + fc1 + relu + fc2 + log_softmax ----------------
__global__ __launch_bounds__(128) void k_mlp(const float* __restrict__ outp, const float* __restrict__ scale_,
                     const float* __restrict__ shift_, const float* __restrict__ fc1w,
                     const float* __restrict__ fc1b, const float* __restrict__ fc2w,
                     const float* __restrict__ fc2b, float* __restrict__ out){
    __shared__ float nrm[F_OUT];
    __shared__ float hid[PENN];
    __shared__ float logit[CC];
    int r = blockIdx.x, t = threadIdx.x;
    for(int j = t; j < F_OUT; j += 128)
        nrm[j] = fmaf(outp[(size_t)r*F_OUT + j], scale_[j], shift_[j]);
    __syncthreads();
    float acc = fc1b[t];
    #pragma unroll 8
    for(int j = 0; j < F_OUT; ++j) acc = fmaf(nrm[j], fc1w[(size_t)t*F_OUT + j], acc);
    hid[t] = acc > 0.f ? acc : 0.f;
    __syncthreads();
    if(t < CC){
        float a = fc2b[t];
        #pragma unroll
        for(int p = 0; p < PENN; ++p) a = fmaf(hid[p], fc2w[t*PENN + p], a);
        logit[t] = a;
    }
    __syncthreads();
    if(t < CC){
        float m = logit[0];
        #pragma unroll
        for(int c = 1; c < CC; ++c) m = fmaxf(m, logit[c]);
        float se = 0.f;
        #pragma unroll
        for(int c = 0; c < CC; ++c) se += expf(logit[c] - m);
        out[r*CC + t] = logit[t] - m - logf(se);
    }
}

extern "C" void kernel_launch(void* const* d_in, const int* in_sizes, int n_in,
                              void* d_out, int out_size, void* d_ws, size_t ws_size,
                              hipStream_t stream){
    const float* x      = (const float*)d_in[0];
    const int*   edges  = (const int*)d_in[1];
    const int*   batch  = (const int*)d_in[2];
    const float* adjh   = (const float*)d_in[3];
    const float* fh     = (const float*)d_in[4];   // z0
    const float* fc_w   = (const float*)d_in[5];
    const float* fc_b   = (const float*)d_in[6];
    const float* rw_w   = (const float*)d_in[7];
    const float* rw_b   = (const float*)d_in[8];
    const float* gamma  = (const float*)d_in[9];
    const float* beta   = (const float*)d_in[10];
    const float* fc1w   = (const float*)d_in[11];
    const float* fc1b   = (const float*)d_in[12];
    const float* fc2w   = (const float*)d_in[13];
    const float* fc2b   = (const float*)d_in[14];
    float* out = (float*)d_out;

    const int* row = edges;
    const int* col = edges + E_EDGES;

    // workspace carve-up
    size_t off = 0;
    auto alloc_f = [&](size_t nf) -> float* {
        float* p = (float*)((char*)d_ws + off);
        off += nf * sizeof(float);
        off = (off + 255) & ~(size_t)255;
        return p;
    };
    float* deg    = alloc_f(N_NODES);
    float* xh     = alloc_f((size_t)N_NODES*DD);
    float* ybuf   = alloc_f((size_t)N_NODES*DD);
    float* agg1   = alloc_f((size_t)N_NODES*DD);
    float* agg2   = alloc_f((size_t)N_NODES*DD);
    float* cur1   = alloc_f((size_t)N_NODES*DD);
    float* cur2   = alloc_f((size_t)N_NODES*DD);
    float* z1     = alloc_f(HH*SS*DD);
    float* z2     = alloc_f(HH*SS*DD);
    float* P      = alloc_f((size_t)3*GG*HS);
    float* outp   = alloc_f((size_t)GG*F_OUT);
    float* scl    = alloc_f(F_OUT);
    float* shf    = alloc_f(F_OUT);
    int*   start  = (int*)alloc_f(GG + 1);
    int*   cnt    = (int*)alloc_f(N_NODES);
    int*   rowptr = (int*)alloc_f(N_NODES + 1);
    int*   cursor = (int*)alloc_f(N_NODES);
    int*   bsum   = (int*)alloc_f(NBLK_SCAN);
    int*   boff   = (int*)alloc_f(NBLK_SCAN);
    int*   erow   = (int*)alloc_f(E_EDGES);

    int blkN = (N_NODES + 255)/256;
    int blkE = (E_EDGES + 255)/256;

    // degree + CSR build (edge-structure only; reused by both gathers)
    k_init_deg<<<blkN, 256, 0, stream>>>(deg);
    k_deg<<<blkE, 256, 0, stream>>>(row, deg);
    k_zero_cnt<<<blkN, 256, 0, stream>>>(cnt);
    k_hist<<<blkE, 256, 0, stream>>>(col, cnt);
    k_scan_bsum<<<NBLK_SCAN, 256, 0, stream>>>(cnt, bsum);
    k_scan_boff<<<1, 512, 0, stream>>>(bsum, boff, rowptr);
    k_scan_final<<<NBLK_SCAN, 256, 0, stream>>>(cnt, boff, rowptr, cursor);
    k_fill<<<blkE, 256, 0, stream>>>(row, col, cursor, erow);

    k_xh<<<1024, 256, 0, stream>>>(x, fc_w, fc_b, deg, xh, ybuf);
    k_gather<<<1024, 256, 0, stream>>>(rowptr, erow, ybuf, agg1);
    k_lin<<<1024, 256, 0, stream>>>(agg1, rw_w, rw_b, deg, cur1, ybuf, 1);
    k_gather<<<1024, 256, 0, stream>>>(rowptr, erow, ybuf, agg2);
    k_lin<<<1024, 256, 0, stream>>>(agg2, rw_w + DD*DD, rw_b + DD, deg, cur2, nullptr, 0);

    k_z<<<1, 256, 0, stream>>>(adjh, fh, z1, z2);
    k_bounds<<<blkN, 256, 0, stream>>>(batch, start);
    k_feat<<<3*GG, 256, 0, stream>>>(fh, z1, z2, xh, cur1, cur2, start, P);
    k_outpre<<<(GG*F_OUT + 255)/256, 256, 0, stream>>>(P, outp);
    k_bnstats<<<F_OUT, 64, 0, stream>>>(outp, gamma, beta, scl, shf);
    k_mlp<<<GG, 128, 0, stream>>>(outp, scl, shf, fc1w, fc1b, fc2w, fc2b, out);
}

// Round 14
// 1062.919 us; speedup vs baseline: 2.1317x; 1.2708x over previous
//
#include <hip/hip_runtime.h>
#include <stdint.h>

#define N_NODES 100000
#define E_EDGES 1600000
#define INDIM 128
#define DD 64
#define HH 16
#define SS 8
#define HS 128            // H*S
#define GG 512
#define PENN 128
#define CC 10
#define F_OUT 384
#define BN_EPS 1e-5f
#define NBLK_SCAN ((N_NODES + 255)/256)   // 391
#define GSPLIT 8

// ---------------- degree (out-degree over row + self loop) ----------------
__global__ void k_init_deg(float* deg){
    int n = blockIdx.x*256 + threadIdx.x;
    if(n < N_NODES) deg[n] = 1.0f;   // self loop
}

__global__ void k_deg(const int* __restrict__ row, float* deg){
    int e = blockIdx.x*256 + threadIdx.x;
    if(e < E_EDGES) atomicAdd(&deg[row[e]], 1.0f);
}

// ---------------- CSR-by-col build (once per launch, reused by both gathers) ----------------
__global__ void k_zero_cnt(int* cnt){
    int n = blockIdx.x*256 + threadIdx.x;
    if(n < N_NODES) cnt[n] = 0;
}

__global__ void k_hist(const int* __restrict__ col, int* __restrict__ cnt){
    int e = blockIdx.x*256 + threadIdx.x;
    if(e < E_EDGES) atomicAdd(&cnt[col[e]], 1);
}

// two-level exclusive scan
__global__ void k_scan_bsum(const int* __restrict__ cnt, int* __restrict__ bsum){
    int b = blockIdx.x, t = threadIdx.x, i = b*256 + t;
    int v = (i < N_NODES) ? cnt[i] : 0;
    #pragma unroll
    for(int off = 32; off; off >>= 1) v += __shfl_down(v, off);
    __shared__ int ws[4];
    if((t & 63) == 0) ws[t >> 6] = v;
    __syncthreads();
    if(t == 0) bsum[b] = ws[0] + ws[1] + ws[2] + ws[3];
}

__global__ __launch_bounds__(512) void k_scan_boff(const int* __restrict__ bsum,
                                                   int* __restrict__ boff,
                                                   int* __restrict__ rowptr){
    __shared__ int buf[512];
    int t = threadIdx.x;
    int v = (t < NBLK_SCAN) ? bsum[t] : 0;
    buf[t] = v;
    __syncthreads();
    for(int off = 1; off < 512; off <<= 1){
        int add = (t >= off) ? buf[t - off] : 0;
        __syncthreads();
        buf[t] += add;
        __syncthreads();
    }
    if(t < NBLK_SCAN) boff[t] = buf[t] - v;
    if(t == 0) rowptr[N_NODES] = buf[511];   // == E_EDGES
}

__global__ void k_scan_final(const int* __restrict__ cnt, const int* __restrict__ boff,
                             int* __restrict__ rowptr, int* __restrict__ cursor){
    int b = blockIdx.x, t = threadIdx.x, i = b*256 + t;
    int lane = t & 63, w = t >> 6;
    int v = (i < N_NODES) ? cnt[i] : 0;
    int x = v;
    #pragma unroll
    for(int off = 1; off < 64; off <<= 1){
        int y = __shfl_up(x, off);
        if(lane >= off) x += y;
    }
    __shared__ int wsum[4];
    if(lane == 63) wsum[w] = x;
    __syncthreads();
    int wpre = 0;
    #pragma unroll
    for(int k = 0; k < 4; ++k) wpre += (k < w) ? wsum[k] : 0;
    int excl = boff[b] + wpre + x - v;
    if(i < N_NODES){ rowptr[i] = excl; cursor[i] = excl; }
}

__global__ void k_fill(const int* __restrict__ row, const int* __restrict__ col,
                       int* __restrict__ cursor, int* __restrict__ erow){
    int e = blockIdx.x*256 + threadIdx.x;
    if(e < E_EDGES){
        int idx = atomicAdd(&cursor[col[e]], 1);
        erow[idx] = row[e];
    }
}

// ---------------- xh = sigmoid(x @ fc_w^T + b); y0 = xh/deg ----------------
__global__ __launch_bounds__(256) void k_xh(const float* __restrict__ x, const float* __restrict__ fc_w,
                     const float* __restrict__ fc_b, const float* __restrict__ deg,
                     float* __restrict__ xh, float* __restrict__ ybuf){
    __shared__ float xl[8][INDIM];      // 4 KB
    int tid  = threadIdx.x;
    int lane = tid & 63;
    int wv   = tid >> 6;                // wave 0..3
    float w[INDIM];
    const float4* wr = (const float4*)(fc_w + (size_t)lane*INDIM);
    #pragma unroll
    for(int q = 0; q < INDIM/4; ++q){
        float4 v = wr[q];
        w[4*q+0] = v.x; w[4*q+1] = v.y; w[4*q+2] = v.z; w[4*q+3] = v.w;
    }
    float bias = fc_b[lane];
    int r = tid >> 5, q0 = tid & 31;    // staging role: row r, quad q0
    #pragma unroll 1
    for(int base = blockIdx.x*8; base < N_NODES; base += gridDim.x*8){
        __syncthreads();
        int nn = base + r;
        float4 v = (nn < N_NODES) ? ((const float4*)(x + (size_t)nn*INDIM))[q0]
                                  : make_float4(0.f,0.f,0.f,0.f);
        ((float4*)xl[r])[q0] = v;
        __syncthreads();
        #pragma unroll
        for(int j = 0; j < 2; ++j){
            int n = base + wv*2 + j;
            if(n < N_NODES){
                const float4* cp = (const float4*)xl[wv*2 + j];
                float a0 = 0.f, a1 = 0.f, a2 = 0.f, a3 = 0.f;
                #pragma unroll
                for(int q = 0; q < INDIM/4; q += 4){
                    float4 v0 = cp[q], v1 = cp[q+1], v2 = cp[q+2], v3 = cp[q+3];
                    a0 = fmaf(v0.x, w[4*q+ 0], a0); a0 = fmaf(v0.y, w[4*q+ 1], a0);
                    a0 = fmaf(v0.z, w[4*q+ 2], a0); a0 = fmaf(v0.w, w[4*q+ 3], a0);
                    a1 = fmaf(v1.x, w[4*q+ 4], a1); a1 = fmaf(v1.y, w[4*q+ 5], a1);
                    a1 = fmaf(v1.z, w[4*q+ 6], a1); a1 = fmaf(v1.w, w[4*q+ 7], a1);
                    a2 = fmaf(v2.x, w[4*q+ 8], a2); a2 = fmaf(v2.y, w[4*q+ 9], a2);
                    a2 = fmaf(v2.z, w[4*q+10], a2); a2 = fmaf(v2.w, w[4*q+11], a2);
                    a3 = fmaf(v3.x, w[4*q+12], a3); a3 = fmaf(v3.y, w[4*q+13], a3);
                    a3 = fmaf(v3.z, w[4*q+14], a3); a3 = fmaf(v3.w, w[4*q+15], a3);
                }
                float acc = bias + ((a0 + a1) + (a2 + a3));
                float s = 1.0f/(1.0f + expf(-acc));
                size_t o = (size_t)n*DD + lane;
                xh[o] = s;
                ybuf[o] = s / deg[n];
            }
        }
    }
}

// ---------------- gather-based aggregation ----------------
__global__ __launch_bounds__(256) void k_gather(const int* __restrict__ rowptr, const int* __restrict__ erow,
                        const float* __restrict__ y, float* __restrict__ agg){
    int lane = threadIdx.x & 63;
    int wave = (blockIdx.x*256 + threadIdx.x) >> 6;
    int nwaves = gridDim.x * 4;
    #pragma unroll 1
    for(int n = wave; n < N_NODES; n += nwaves){
        int b = rowptr[n], en = rowptr[n+1];
        float acc = y[(size_t)n*DD + lane];    // self loop
        #pragma unroll 2
        for(int j = b; j < en; ++j){
            int rr = erow[j];
            acc += y[(size_t)rr*DD + lane];
        }
        agg[(size_t)n*DD + lane] = acc;
    }
}

// ---------------- cur = agg @ w^T + b ; optionally y_next = cur/deg ----------------
__global__ __launch_bounds__(256) void k_lin(const float* __restrict__ agg, const float* __restrict__ w_,
                     const float* __restrict__ b, const float* __restrict__ deg,
                     float* __restrict__ cur, float* __restrict__ ynext, int make_next){
    int lane = threadIdx.x & 63;
    int wave = (blockIdx.x*256 + threadIdx.x) >> 6;
    int nwaves = gridDim.x * 4;
    float w[DD];
    const float4* wr = (const float4*)(w_ + (size_t)lane*DD);
    #pragma unroll
    for(int q = 0; q < DD/4; ++q){
        float4 v = wr[q];
        w[4*q+0] = v.x; w[4*q+1] = v.y; w[4*q+2] = v.z; w[4*q+3] = v.w;
    }
    float bias = b[lane];
    #pragma unroll 1
    for(int n = wave; n < N_NODES; n += nwaves){
        const float4* ar = (const float4*)(agg + (size_t)n*DD);
        float acc = bias;
        #pragma unroll
        for(int q = 0; q < DD/4; ++q){
            float4 v = ar[q];
            acc = fmaf(v.x, w[4*q+0], acc);
            acc = fmaf(v.y, w[4*q+1], acc);
            acc = fmaf(v.z, w[4*q+2], acc);
            acc = fmaf(v.w, w[4*q+3], acc);
        }
        size_t o = (size_t)n*DD + lane;
        cur[o] = acc;
        if(make_next) ynext[o] = acc / deg[n];
    }
}

// ---------------- A1 = relu-sym(adj_hidden), A2 = A1@A1 (per head) ----------------
__global__ void k_adj(const float* __restrict__ adj_hidden,
                      float* __restrict__ A1g, float* __restrict__ A2g){
    __shared__ float A[HH][SS][SS];
    int tid = threadIdx.x;
    for(int i = tid; i < HH*SS*SS; i += 256) ((float*)A)[i] = 0.0f;
    __syncthreads();
    for(int i = tid; i < HH*28; i += 256){
        int h = i / 28, p = i % 28;
        int iu = 0, ju = 0, cnt = 0;
        for(int a = 0; a < SS-1; ++a){
            int rl = SS-1-a;
            if(p < cnt + rl){ iu = a; ju = a + 1 + (p - cnt); break; }
            cnt += rl;
        }
        float v = adj_hidden[i];
        v = v > 0.f ? v : 0.f;
        A[h][iu][ju] = v;
        A[h][ju][iu] = v;
    }
    __syncthreads();
    for(int i = tid; i < HH*SS*SS; i += 256){
        int h = i >> 6, s = (i >> 3) & 7, b = i & 7;
        A1g[i] = A[h][s][b];
        float acc = 0.f;
        #pragma unroll
        for(int k = 0; k < SS; ++k) acc += A[h][s][k] * A[h][k][b];
        A2g[i] = acc;
    }
}

// ---------------- graph boundaries from sorted batch ----------------
__global__ void k_bounds(const int* __restrict__ batch, int* __restrict__ start){
    int n = blockIdx.x*256 + threadIdx.x;
    if(n >= N_NODES) return;
    int b = batch[n];
    int prev = (n == 0) ? -1 : batch[n-1];
    for(int g = prev + 1; g <= b; ++g) start[g] = n;
    if(n == N_NODES-1){
        for(int g = b + 1; g <= GG; ++g) start[g] = N_NODES;
    }
}

__global__ void k_zero_P(float* P){
    int i = blockIdx.x*256 + threadIdx.x;
    if(i < 3*GG*HS) P[i] = 0.f;
}

// ---------------- fused feature reduce, all 3 steps, z0-dots only ----------------
// dt_i[h,s] = sum_b A^i[h,s,b] * (z0[h,b]·cur_i[n])  — A-mix via 8-lane shuffles.
// grid = GSPLIT*GG blocks; block = 256 = 128 hs × 2 slots. z0 row + A rows in regs;
// xh/cur1/cur2 chunks in LDS (uniform-address broadcast reads). Partial sums
// atomicAdd'ed into pre-zeroed P (fp32 reassociation only).
__global__ __launch_bounds__(256) void k_feat(const float* __restrict__ z0,
                      const float* __restrict__ A1g, const float* __restrict__ A2g,
                      const float* __restrict__ xh, const float* __restrict__ cur1,
                      const float* __restrict__ cur2,
                      const int* __restrict__ start, float* __restrict__ P){
    __shared__ float xhl[8][DD];
    __shared__ float c1l[8][DD];
    __shared__ float c2l[8][DD];
    __shared__ float red[HS][3];
    int tid  = threadIdx.x;
    int lane = tid & 63;
    int hs   = tid & 127;
    int slot = tid >> 7;           // 0 or 1
    int g = blockIdx.x / GSPLIT;
    int q = blockIdx.x - g*GSPLIT;
    int s0 = start[g], s1 = start[g+1];

    // z0 row + A rows -> registers (static indexing)
    float zr[DD];
    {
        const float4* zp = (const float4*)(z0 + (size_t)hs*DD);
        #pragma unroll
        for(int qq = 0; qq < 16; ++qq){
            float4 v = zp[qq];
            zr[4*qq+0]=v.x; zr[4*qq+1]=v.y; zr[4*qq+2]=v.z; zr[4*qq+3]=v.w;
        }
    }
    float a1r[8], a2r[8];
    #pragma unroll
    for(int b = 0; b < 8; ++b){
        a1r[b] = A1g[hs*8 + b];
        a2r[b] = A2g[hs*8 + b];
    }

    float acc0 = 0.f, acc1 = 0.f, acc2 = 0.f;
    #pragma unroll 1
    for(int base = s0 + q*8; base < s1; base += 8*GSPLIT){
        __syncthreads();
        #pragma unroll
        for(int k = 0; k < 2; ++k){
            int idx = tid + k*256;              // 0..511
            int nn = base + (idx >> 6);
            int d  = idx & 63;
            bool ok = nn < s1;
            size_t off = (size_t)nn*DD + d;
            xhl[idx >> 6][d] = ok ? xh  [off] : 0.f;
            c1l[idx >> 6][d] = ok ? cur1[off] : 0.f;
            c2l[idx >> 6][d] = ok ? cur2[off] : 0.f;
        }
        __syncthreads();
        #pragma unroll
        for(int j = 0; j < 4; ++j){
            int n = base + slot*4 + j;
            if(n < s1){                          // wave-uniform branch
                const float4* xp = (const float4*)(xhl[slot*4 + j]);
                const float4* p1 = (const float4*)(c1l[slot*4 + j]);
                const float4* p2 = (const float4*)(c2l[slot*4 + j]);
                float zx = 0.f, u1 = 0.f, u2 = 0.f;   // three independent chains
                #pragma unroll
                for(int qq = 0; qq < 16; ++qq){
                    float4 a = xp[qq], b = p1[qq], c = p2[qq];
                    zx = fmaf(a.x, zr[4*qq+0], zx);
                    zx = fmaf(a.y, zr[4*qq+1], zx);
                    zx = fmaf(a.z, zr[4*qq+2], zx);
                    zx = fmaf(a.w, zr[4*qq+3], zx);
                    u1 = fmaf(b.x, zr[4*qq+0], u1);
                    u1 = fmaf(b.y, zr[4*qq+1], u1);
                    u1 = fmaf(b.z, zr[4*qq+2], u1);
                    u1 = fmaf(b.w, zr[4*qq+3], u1);
                    u2 = fmaf(c.x, zr[4*qq+0], u2);
                    u2 = fmaf(c.y, zr[4*qq+1], u2);
                    u2 = fmaf(c.z, zr[4*qq+2], u2);
                    u2 = fmaf(c.w, zr[4*qq+3], u2);
                }
                float dt1 = 0.f, dt2 = 0.f;
                int gb = lane & 56;               // 8-lane h-group base
                #pragma unroll
                for(int b = 0; b < 8; ++b){
                    float v1 = __shfl(u1, gb + b);
                    float v2 = __shfl(u2, gb + b);
                    dt1 = fmaf(a1r[b], v1, dt1);
                    dt2 = fmaf(a2r[b], v2, dt2);
                }
                acc0 = fmaf(zx, zx,  acc0);
                acc1 = fmaf(zx, dt1, acc1);
                acc2 = fmaf(zx, dt2, acc2);
            }
        }
    }
    __syncthreads();
    if(slot == 1){ red[hs][0] = acc0; red[hs][1] = acc1; red[hs][2] = acc2; }
    __syncthreads();
    if(slot == 0){
        atomicAdd(&P[(size_t)0*GG*HS + (size_t)g*HS + hs], acc0 + red[hs][0]);
        atomicAdd(&P[(size_t)1*GG*HS + (size_t)g*HS + hs], acc1 + red[hs][1]);
        atomicAdd(&P[(size_t)2*GG*HS + (size_t)g*HS + hs], acc2 + red[hs][2]);
    }
}

// ---------------- scrambled reshape: out_pre[r][i*128+c] = P_i[g,h,s] ----------------
__global__ void k_outpre(const float* __restrict__ P, float* __restrict__ outp){
    int idx = blockIdx.x*256 + threadIdx.x;
    if(idx >= GG*F_OUT) return;
    int r = idx / F_OUT, j = idx % F_OUT;
    int i = j >> 7, c = j & 127;
    int g = ((r & 63) << 3) + (c >> 4);
    int h = c & 15, s = r >> 6;
    int hs = h*SS + s;
    outp[idx] = P[((size_t)i*GG + g)*HS + hs];
}

// ---------------- batchnorm stats per column ----------------
__global__ void k_bnstats(const float* __restrict__ outp, const float* __restrict__ gamma,
                          const float* __restrict__ beta, float* __restrict__ scale_,
                          float* __restrict__ shift_){
    int j = blockIdx.x;     // 384 columns
    int t = threadIdx.x;    // 64 threads
    float v[8];
    float sum = 0.f;
    #pragma unroll
    for(int i = 0; i < 8; ++i){ v[i] = outp[(size_t)(t*8+i)*F_OUT + j]; sum += v[i]; }
    #pragma unroll
    for(int off = 32; off; off >>= 1) sum += __shfl_down(sum, off);
    sum = __shfl(sum, 0);
    float mean = sum / (float)GG;
    float sq = 0.f;
    #pragma unroll
    for(int i = 0; i < 8; ++i){ float d = v[i] - mean; sq = fmaf(d, d, sq); }
    #pragma unroll
    for(int off = 32; off; off >>= 1) sq += __shfl_down(sq, off);
    if(t == 0){
        float var = sq / (float)GG;
        float rstd = rsqrtf(var + BN_EPS);
        float sc = rstd * gamma[j];
        scale_[j] = sc;
        shift_[j] = beta[j] - mean*sc;
    }
}

// ---------------- BN apply + fc1 + relu + fc2 + log_softmax ----------------
__global__ __launch_bounds__(128) void k_mlp(const float* __restrict__ outp, const float* __restrict__ scale_,
                     const float* __restrict__ shift_, const float* __restrict__ fc1w,
                     const float* __restrict__ fc1b, const float* __restrict__ fc2w,
                     const float* __restrict__ fc2b, float* __restrict__ out){
    __shared__ float nrm[F_OUT];
    __shared__ float hid[PENN];
    __shared__ float logit[CC];
    int r = blockIdx.x, t = threadIdx.x;
    for(int j = t; j < F_OUT; j += 128)
        nrm[j] = fmaf(outp[(size_t)r*F_OUT + j], scale_[j], shift_[j]);
    __syncthreads();
    float acc = fc1b[t];
    #pragma unroll 8
    for(int j = 0; j < F_OUT; ++j) acc = fmaf(nrm[j], fc1w[(size_t)t*F_OUT + j], acc);
    hid[t] = acc > 0.f ? acc : 0.f;
    __syncthreads();
    if(t < CC){
        float a = fc2b[t];
        #pragma unroll
        for(int p = 0; p < PENN; ++p) a = fmaf(hid[p], fc2w[t*PENN + p], a);
        logit[t] = a;
    }
    __syncthreads();
    if(t < CC){
        float m = logit[0];
        #pragma unroll
        for(int c = 1; c < CC; ++c) m = fmaxf(m, logit[c]);
        float se = 0.f;
        #pragma unroll
        for(int c = 0; c < CC; ++c) se += expf(logit[c] - m);
        out[r*CC + t] = logit[t] - m - logf(se);
    }
}

extern "C" void kernel_launch(void* const* d_in, const int* in_sizes, int n_in,
                              void* d_out, int out_size, void* d_ws, size_t ws_size,
                              hipStream_t stream){
    const float* x      = (const float*)d_in[0];
    const int*   edges  = (const int*)d_in[1];
    const int*   batch  = (const int*)d_in[2];
    const float* adjh   = (const float*)d_in[3];
    const float* fh     = (const float*)d_in[4];   // z0
    const float* fc_w   = (const float*)d_in[5];
    const float* fc_b   = (const float*)d_in[6];
    const float* rw_w   = (const float*)d_in[7];
    const float* rw_b   = (const float*)d_in[8];
    const float* gamma  = (const float*)d_in[9];
    const float* beta   = (const float*)d_in[10];
    const float* fc1w   = (const float*)d_in[11];
    const float* fc1b   = (const float*)d_in[12];
    const float* fc2w   = (const float*)d_in[13];
    const float* fc2b   = (const float*)d_in[14];
    float* out = (float*)d_out;

    const int* row = edges;
    const int* col = edges + E_EDGES;

    // workspace carve-up
    size_t off = 0;
    auto alloc_f = [&](size_t nf) -> float* {
        float* p = (float*)((char*)d_ws + off);
        off += nf * sizeof(float);
        off = (off + 255) & ~(size_t)255;
        return p;
    };
    float* deg    = alloc_f(N_NODES);
    float* xh     = alloc_f((size_t)N_NODES*DD);
    float* ybuf   = alloc_f((size_t)N_NODES*DD);
    float* agg1   = alloc_f((size_t)N_NODES*DD);
    float* agg2   = alloc_f((size_t)N_NODES*DD);
    float* cur1   = alloc_f((size_t)N_NODES*DD);
    float* cur2   = alloc_f((size_t)N_NODES*DD);
    float* A1g    = alloc_f(HH*SS*SS);
    float* A2g    = alloc_f(HH*SS*SS);
    float* P      = alloc_f((size_t)3*GG*HS);
    float* outp   = alloc_f((size_t)GG*F_OUT);
    float* scl    = alloc_f(F_OUT);
    float* shf    = alloc_f(F_OUT);
    int*   start  = (int*)alloc_f(GG + 1);
    int*   cnt    = (int*)alloc_f(N_NODES);
    int*   rowptr = (int*)alloc_f(N_NODES + 1);
    int*   cursor = (int*)alloc_f(N_NODES);
    int*   bsum   = (int*)alloc_f(NBLK_SCAN);
    int*   boff   = (int*)alloc_f(NBLK_SCAN);
    int*   erow   = (int*)alloc_f(E_EDGES);

    int blkN = (N_NODES + 255)/256;
    int blkE = (E_EDGES + 255)/256;

    // degree + CSR build (edge-structure only; reused by both gathers)
    k_init_deg<<<blkN, 256, 0, stream>>>(deg);
    k_deg<<<blkE, 256, 0, stream>>>(row, deg);
    k_zero_cnt<<<blkN, 256, 0, stream>>>(cnt);
    k_hist<<<blkE, 256, 0, stream>>>(col, cnt);
    k_scan_bsum<<<NBLK_SCAN, 256, 0, stream>>>(cnt, bsum);
    k_scan_boff<<<1, 512, 0, stream>>>(bsum, boff, rowptr);
    k_scan_final<<<NBLK_SCAN, 256, 0, stream>>>(cnt, boff, rowptr, cursor);
    k_fill<<<blkE, 256, 0, stream>>>(row, col, cursor, erow);

    k_xh<<<1024, 256, 0, stream>>>(x, fc_w, fc_b, deg, xh, ybuf);
    k_gather<<<1024, 256, 0, stream>>>(rowptr, erow, ybuf, agg1);
    k_lin<<<1024, 256, 0, stream>>>(agg1, rw_w, rw_b, deg, cur1, ybuf, 1);
    k_gather<<<1024, 256, 0, stream>>>(rowptr, erow, ybuf, agg2);
    k_lin<<<1024, 256, 0, stream>>>(agg2, rw_w + DD*DD, rw_b + DD, deg, cur2, nullptr, 0);

    k_adj<<<1, 256, 0, stream>>>(adjh, A1g, A2g);
    k_bounds<<<blkN, 256, 0, stream>>>(batch, start);
    k_zero_P<<<(3*GG*HS + 255)/256, 256, 0, stream>>>(P);
    k_feat<<<GSPLIT*GG, 256, 0, stream>>>(fh, A1g, A2g, xh, cur1, cur2, start, P);
    k_outpre<<<(GG*F_OUT + 255)/256, 256, 0, stream>>>(P, outp);
    k_bnstats<<<F_OUT, 64, 0, stream>>>(outp, gamma, beta, scl, shf);
    k_mlp<<<GG, 128, 0, stream>>>(outp, scl, shf, fc1w, fc1b, fc2w, fc2b, out);
}

// Round 15
// 959.629 us; speedup vs baseline: 2.3612x; 1.1076x over previous
//
#include <hip/hip_runtime.h>
#include <stdint.h>

#define N_NODES 100000
#define E_EDGES 1600000
#define INDIM 128
#define DD 64
#define HH 16
#define SS 8
#define HS 128            // H*S
#define GG 512
#define PENN 128
#define CC 10
#define F_OUT 384
#define BN_EPS 1e-5f
#define NBLK_SCAN ((N_NODES + 255)/256)   // 391
#define GSPLIT 8

// ---------------- zero both degree-count arrays ----------------
__global__ void k_zero_cnts(int* cnt_row, int* cnt_col){
    int n = blockIdx.x*256 + threadIdx.x;
    if(n < N_NODES){ cnt_row[n] = 0; cnt_col[n] = 0; }
}

// ---------------- fused degree: out-degree(row) + in-degree(col) in one edge pass ----------------
__global__ void k_deg_hist(const int* __restrict__ row, const int* __restrict__ col,
                           int* __restrict__ cnt_row, int* __restrict__ cnt_col){
    int e = blockIdx.x*256 + threadIdx.x;
    if(e < E_EDGES){
        atomicAdd(&cnt_row[row[e]], 1);
        atomicAdd(&cnt_col[col[e]], 1);
    }
}

// two-level exclusive scan over cnt_col
__global__ void k_scan_bsum(const int* __restrict__ cnt, int* __restrict__ bsum){
    int b = blockIdx.x, t = threadIdx.x, i = b*256 + t;
    int v = (i < N_NODES) ? cnt[i] : 0;
    #pragma unroll
    for(int off = 32; off; off >>= 1) v += __shfl_down(v, off);
    __shared__ int ws[4];
    if((t & 63) == 0) ws[t >> 6] = v;
    __syncthreads();
    if(t == 0) bsum[b] = ws[0] + ws[1] + ws[2] + ws[3];
}

__global__ __launch_bounds__(512) void k_scan_boff(const int* __restrict__ bsum,
                                                   int* __restrict__ boff,
                                                   int* __restrict__ rowptr){
    __shared__ int buf[512];
    int t = threadIdx.x;
    int v = (t < NBLK_SCAN) ? bsum[t] : 0;
    buf[t] = v;
    __syncthreads();
    for(int off = 1; off < 512; off <<= 1){
        int add = (t >= off) ? buf[t - off] : 0;
        __syncthreads();
        buf[t] += add;
        __syncthreads();
    }
    if(t < NBLK_SCAN) boff[t] = buf[t] - v;
    if(t == 0) rowptr[N_NODES] = buf[511];   // == E_EDGES
}

__global__ void k_scan_final(const int* __restrict__ cnt, const int* __restrict__ boff,
                             int* __restrict__ rowptr, int* __restrict__ cursor){
    int b = blockIdx.x, t = threadIdx.x, i = b*256 + t;
    int lane = t & 63, w = t >> 6;
    int v = (i < N_NODES) ? cnt[i] : 0;
    int x = v;
    #pragma unroll
    for(int off = 1; off < 64; off <<= 1){
        int y = __shfl_up(x, off);
        if(lane >= off) x += y;
    }
    __shared__ int wsum[4];
    if(lane == 63) wsum[w] = x;
    __syncthreads();
    int wpre = 0;
    #pragma unroll
    for(int k = 0; k < 4; ++k) wpre += (k < w) ? wsum[k] : 0;
    int excl = boff[b] + wpre + x - v;
    if(i < N_NODES){ rowptr[i] = excl; cursor[i] = excl; }
}

__global__ void k_fill(const int* __restrict__ row, const int* __restrict__ col,
                       int* __restrict__ cursor, int* __restrict__ erow){
    int e = blockIdx.x*256 + threadIdx.x;
    if(e < E_EDGES){
        int idx = atomicAdd(&cursor[col[e]], 1);
        erow[idx] = row[e];
    }
}

// ---------------- xh = sigmoid(x @ fc_w^T + b); y0 = xh/deg ----------------
__global__ __launch_bounds__(256) void k_xh(const float* __restrict__ x, const float* __restrict__ fc_w,
                     const float* __restrict__ fc_b, const int* __restrict__ cnt_row,
                     float* __restrict__ xh, float* __restrict__ ybuf){
    __shared__ float xl[8][INDIM];      // 4 KB
    int tid  = threadIdx.x;
    int lane = tid & 63;
    int wv   = tid >> 6;                // wave 0..3
    float w[INDIM];
    const float4* wr = (const float4*)(fc_w + (size_t)lane*INDIM);
    #pragma unroll
    for(int q = 0; q < INDIM/4; ++q){
        float4 v = wr[q];
        w[4*q+0] = v.x; w[4*q+1] = v.y; w[4*q+2] = v.z; w[4*q+3] = v.w;
    }
    float bias = fc_b[lane];
    int r = tid >> 5, q0 = tid & 31;    // staging role: row r, quad q0
    #pragma unroll 1
    for(int base = blockIdx.x*8; base < N_NODES; base += gridDim.x*8){
        __syncthreads();
        int nn = base + r;
        float4 v = (nn < N_NODES) ? ((const float4*)(x + (size_t)nn*INDIM))[q0]
                                  : make_float4(0.f,0.f,0.f,0.f);
        ((float4*)xl[r])[q0] = v;
        __syncthreads();
        #pragma unroll
        for(int j = 0; j < 2; ++j){
            int n = base + wv*2 + j;
            if(n < N_NODES){
                const float4* cp = (const float4*)xl[wv*2 + j];
                float a0 = 0.f, a1 = 0.f, a2 = 0.f, a3 = 0.f;
                #pragma unroll
                for(int q = 0; q < INDIM/4; q += 4){
                    float4 v0 = cp[q], v1 = cp[q+1], v2 = cp[q+2], v3 = cp[q+3];
                    a0 = fmaf(v0.x, w[4*q+ 0], a0); a0 = fmaf(v0.y, w[4*q+ 1], a0);
                    a0 = fmaf(v0.z, w[4*q+ 2], a0); a0 = fmaf(v0.w, w[4*q+ 3], a0);
                    a1 = fmaf(v1.x, w[4*q+ 4], a1); a1 = fmaf(v1.y, w[4*q+ 5], a1);
                    a1 = fmaf(v1.z, w[4*q+ 6], a1); a1 = fmaf(v1.w, w[4*q+ 7], a1);
                    a2 = fmaf(v2.x, w[4*q+ 8], a2); a2 = fmaf(v2.y, w[4*q+ 9], a2);
                    a2 = fmaf(v2.z, w[4*q+10], a2); a2 = fmaf(v2.w, w[4*q+11], a2);
                    a3 = fmaf(v3.x, w[4*q+12], a3); a3 = fmaf(v3.y, w[4*q+13], a3);
                    a3 = fmaf(v3.z, w[4*q+14], a3); a3 = fmaf(v3.w, w[4*q+15], a3);
                }
                float acc = bias + ((a0 + a1) + (a2 + a3));
                float s = 1.0f/(1.0f + expf(-acc));
                size_t o = (size_t)n*DD + lane;
                xh[o] = s;
                ybuf[o] = s / (float)(cnt_row[n] + 1);
            }
        }
    }
}

// ---------------- fused gather + linear: cur[n] = W·(y[n] + sum y[erow]) + b ----------------
// one wave per node. Gather acc per lane, transpose via per-wave LDS row, then
// dot with register-resident W row (lane d owns w[d][:]). ynext to SEPARATE buffer.
__global__ __launch_bounds__(256) void k_gather_lin(const int* __restrict__ rowptr, const int* __restrict__ erow,
                        const float* __restrict__ y, const float* __restrict__ w_,
                        const float* __restrict__ b, const int* __restrict__ cnt_row,
                        float* __restrict__ cur, float* __restrict__ ynext, int make_next){
    __shared__ float aggl[4][DD];
    int lane = threadIdx.x & 63;
    int wv   = threadIdx.x >> 6;
    int wave = (blockIdx.x*256 + threadIdx.x) >> 6;
    int nwaves = gridDim.x * 4;
    float w[DD];
    const float4* wr = (const float4*)(w_ + (size_t)lane*DD);
    #pragma unroll
    for(int q = 0; q < DD/4; ++q){
        float4 v = wr[q];
        w[4*q+0] = v.x; w[4*q+1] = v.y; w[4*q+2] = v.z; w[4*q+3] = v.w;
    }
    float bias = b[lane];
    #pragma unroll 1
    for(int n = wave; n < N_NODES; n += nwaves){
        int bb = rowptr[n], en = rowptr[n+1];
        float acc = y[(size_t)n*DD + lane];    // self loop
        #pragma unroll 2
        for(int j = bb; j < en; ++j){
            int rr = erow[j];
            acc += y[(size_t)rr*DD + lane];
        }
        aggl[wv][lane] = acc;                  // wave-private LDS row
        __threadfence_block();                 // order write -> broadcast reads (same wave)
        const float4* ap = (const float4*)aggl[wv];
        float a0 = 0.f, a1 = 0.f;
        #pragma unroll
        for(int q = 0; q < DD/4; q += 2){
            float4 v0 = ap[q], v1 = ap[q+1];
            a0 = fmaf(v0.x, w[4*q+0], a0); a0 = fmaf(v0.y, w[4*q+1], a0);
            a0 = fmaf(v0.z, w[4*q+2], a0); a0 = fmaf(v0.w, w[4*q+3], a0);
            a1 = fmaf(v1.x, w[4*q+4], a1); a1 = fmaf(v1.y, w[4*q+5], a1);
            a1 = fmaf(v1.z, w[4*q+6], a1); a1 = fmaf(v1.w, w[4*q+7], a1);
        }
        float outv = bias + a0 + a1;
        size_t o = (size_t)n*DD + lane;
        cur[o] = outv;
        if(make_next) ynext[o] = outv / (float)(cnt_row[n] + 1);
        __threadfence_block();                 // reads done before next-iter overwrite
    }
}

// ---------------- A1 = relu-sym(adj_hidden), A2 = A1@A1 (per head) ----------------
__global__ void k_adj(const float* __restrict__ adj_hidden,
                      float* __restrict__ A1g, float* __restrict__ A2g){
    __shared__ float A[HH][SS][SS];
    int tid = threadIdx.x;
    for(int i = tid; i < HH*SS*SS; i += 256) ((float*)A)[i] = 0.0f;
    __syncthreads();
    for(int i = tid; i < HH*28; i += 256){
        int h = i / 28, p = i % 28;
        int iu = 0, ju = 0, cnt = 0;
        for(int a = 0; a < SS-1; ++a){
            int rl = SS-1-a;
            if(p < cnt + rl){ iu = a; ju = a + 1 + (p - cnt); break; }
            cnt += rl;
        }
        float v = adj_hidden[i];
        v = v > 0.f ? v : 0.f;
        A[h][iu][ju] = v;
        A[h][ju][iu] = v;
    }
    __syncthreads();
    for(int i = tid; i < HH*SS*SS; i += 256){
        int h = i >> 6, s = (i >> 3) & 7, b = i & 7;
        A1g[i] = A[h][s][b];
        float acc = 0.f;
        #pragma unroll
        for(int k = 0; k < SS; ++k) acc += A[h][s][k] * A[h][k][b];
        A2g[i] = acc;
    }
}

// ---------------- graph boundaries from sorted batch ----------------
__global__ void k_bounds(const int* __restrict__ batch, int* __restrict__ start){
    int n = blockIdx.x*256 + threadIdx.x;
    if(n >= N_NODES) return;
    int b = batch[n];
    int prev = (n == 0) ? -1 : batch[n-1];
    for(int g = prev + 1; g <= b; ++g) start[g] = n;
    if(n == N_NODES-1){
        for(int g = b + 1; g <= GG; ++g) start[g] = N_NODES;
    }
}

__global__ void k_zero_P(float* P){
    int i = blockIdx.x*256 + threadIdx.x;
    if(i < 3*GG*HS) P[i] = 0.f;
}

// ---------------- fused feature reduce, all 3 steps, z0-dots only, double-buffered ----------------
__global__ __launch_bounds__(256) void k_feat(const float* __restrict__ z0,
                      const float* __restrict__ A1g, const float* __restrict__ A2g,
                      const float* __restrict__ xh, const float* __restrict__ cur1,
                      const float* __restrict__ cur2,
                      const int* __restrict__ start, float* __restrict__ P){
    __shared__ float xhl[2][8][DD];
    __shared__ float c1l[2][8][DD];
    __shared__ float c2l[2][8][DD];
    __shared__ float red[HS][3];
    int tid  = threadIdx.x;
    int lane = tid & 63;
    int hs   = tid & 127;
    int slot = tid >> 7;           // 0 or 1
    int g = blockIdx.x / GSPLIT;
    int q = blockIdx.x - g*GSPLIT;
    int s0 = start[g], s1 = start[g+1];
    const int STEP = 8*GSPLIT;

    // z0 row + A rows -> registers (static indexing)
    float zr[DD];
    {
        const float4* zp = (const float4*)(z0 + (size_t)hs*DD);
        #pragma unroll
        for(int qq = 0; qq < 16; ++qq){
            float4 v = zp[qq];
            zr[4*qq+0]=v.x; zr[4*qq+1]=v.y; zr[4*qq+2]=v.z; zr[4*qq+3]=v.w;
        }
    }
    float a1r[8], a2r[8];
    #pragma unroll
    for(int b = 0; b < 8; ++b){
        a1r[b] = A1g[hs*8 + b];
        a2r[b] = A2g[hs*8 + b];
    }

    // stage helper (inlined twice below): loads 8 node-rows of xh/cur1/cur2 into buf
    auto stage = [&](int base, int buf){
        #pragma unroll
        for(int k = 0; k < 2; ++k){
            int idx = tid + k*256;              // 0..511
            int nn = base + (idx >> 6);
            int d  = idx & 63;
            bool ok = nn < s1;
            size_t off = (size_t)nn*DD + d;
            xhl[buf][idx >> 6][d] = ok ? xh  [off] : 0.f;
            c1l[buf][idx >> 6][d] = ok ? cur1[off] : 0.f;
            c2l[buf][idx >> 6][d] = ok ? cur2[off] : 0.f;
        }
    };

    float acc0 = 0.f, acc1 = 0.f, acc2 = 0.f;
    int first = s0 + q*8;
    int cur = 0;
    if(first < s1) stage(first, 0);
    #pragma unroll 1
    for(int base = first; base < s1; base += STEP){
        __syncthreads();                       // current buffer staged
        int nb = base + STEP;
        if(nb < s1) stage(nb, cur ^ 1);        // prefetch next while computing
        #pragma unroll
        for(int j = 0; j < 4; ++j){
            int n = base + slot*4 + j;
            if(n < s1){                         // wave-uniform branch
                const float4* xp = (const float4*)(xhl[cur][slot*4 + j]);
                const float4* p1 = (const float4*)(c1l[cur][slot*4 + j]);
                const float4* p2 = (const float4*)(c2l[cur][slot*4 + j]);
                float zx = 0.f, u1 = 0.f, u2 = 0.f;   // three independent chains
                #pragma unroll
                for(int qq = 0; qq < 16; ++qq){
                    float4 a = xp[qq], b = p1[qq], c = p2[qq];
                    zx = fmaf(a.x, zr[4*qq+0], zx);
                    zx = fmaf(a.y, zr[4*qq+1], zx);
                    zx = fmaf(a.z, zr[4*qq+2], zx);
                    zx = fmaf(a.w, zr[4*qq+3], zx);
                    u1 = fmaf(b.x, zr[4*qq+0], u1);
                    u1 = fmaf(b.y, zr[4*qq+1], u1);
                    u1 = fmaf(b.z, zr[4*qq+2], u1);
                    u1 = fmaf(b.w, zr[4*qq+3], u1);
                    u2 = fmaf(c.x, zr[4*qq+0], u2);
                    u2 = fmaf(c.y, zr[4*qq+1], u2);
                    u2 = fmaf(c.z, zr[4*qq+2], u2);
                    u2 = fmaf(c.w, zr[4*qq+3], u2);
                }
                float dt1 = 0.f, dt2 = 0.f;
                int gb = lane & 56;               // 8-lane h-group base
                #pragma unroll
                for(int b = 0; b < 8; ++b){
                    float v1 = __shfl(u1, gb + b);
                    float v2 = __shfl(u2, gb + b);
                    dt1 = fmaf(a1r[b], v1, dt1);
                    dt2 = fmaf(a2r[b], v2, dt2);
                }
                acc0 = fmaf(zx, zx,  acc0);
                acc1 = fmaf(zx, dt1, acc1);
                acc2 = fmaf(zx, dt2, acc2);
            }
        }
        cur ^= 1;
    }
    __syncthreads();
    if(slot == 1){ red[hs][0] = acc0; red[hs][1] = acc1; red[hs][2] = acc2; }
    __syncthreads();
    if(slot == 0){
        atomicAdd(&P[(size_t)0*GG*HS + (size_t)g*HS + hs], acc0 + red[hs][0]);
        atomicAdd(&P[(size_t)1*GG*HS + (size_t)g*HS + hs], acc1 + red[hs][1]);
        atomicAdd(&P[(size_t)2*GG*HS + (size_t)g*HS + hs], acc2 + red[hs][2]);
    }
}

// ---------------- scrambled reshape: out_pre[r][i*128+c] = P_i[g,h,s] ----------------
__global__ void k_outpre(const float* __restrict__ P, float* __restrict__ outp){
    int idx = blockIdx.x*256 + threadIdx.x;
    if(idx >= GG*F_OUT) return;
    int r = idx / F_OUT, j = idx % F_OUT;
    int i = j >> 7, c = j & 127;
    int g = ((r & 63) << 3) + (c >> 4);
    int h = c & 15, s = r >> 6;
    int hs = h*SS + s;
    outp[idx] = P[((size_t)i*GG + g)*HS + hs];
}

// ---------------- batchnorm stats per column ----------------
__global__ void k_bnstats(const float* __restrict__ outp, const float* __restrict__ gamma,
                          const float* __restrict__ beta, float* __restrict__ scale_,
                          float* __restrict__ shift_){
    int j = blockIdx.x;     // 384 columns
    int t = threadIdx.x;    // 64 threads
    float v[8];
    float sum = 0.f;
    #pragma unroll
    for(int i = 0; i < 8; ++i){ v[i] = outp[(size_t)(t*8+i)*F_OUT + j]; sum += v[i]; }
    #pragma unroll
    for(int off = 32; off; off >>= 1) sum += __shfl_down(sum, off);
    sum = __shfl(sum, 0);
    float mean = sum / (float)GG;
    float sq = 0.f;
    #pragma unroll
    for(int i = 0; i < 8; ++i){ float d = v[i] - mean; sq = fmaf(d, d, sq); }
    #pragma unroll
    for(int off = 32; off; off >>= 1) sq += __shfl_down(sq, off);
    if(t == 0){
        float var = sq / (float)GG;
        float rstd = rsqrtf(var + BN_EPS);
        float sc = rstd * gamma[j];
        scale_[j] = sc;
        shift_[j] = beta[j] - mean*sc;
    }
}

// ---------------- BN apply + fc1 + relu + fc2 + log_softmax ----------------
__global__ __launch_bounds__(128) void k_mlp(const float* __restrict__ outp, const float* __restrict__ scale_,
                     const float* __restrict__ shift_, const float* __restrict__ fc1w,
                     const float* __restrict__ fc1b, const float* __restrict__ fc2w,
                     const float* __restrict__ fc2b, float* __restrict__ out){
    __shared__ float nrm[F_OUT];
    __shared__ float hid[PENN];
    __shared__ float logit[CC];
    int r = blockIdx.x, t = threadIdx.x;
    for(int j = t; j < F_OUT; j += 128)
        nrm[j] = fmaf(outp[(size_t)r*F_OUT + j], scale_[j], shift_[j]);
    __syncthreads();
    float acc = fc1b[t];
    #pragma unroll 8
    for(int j = 0; j < F_OUT; ++j) acc = fmaf(nrm[j], fc1w[(size_t)t*F_OUT + j], acc);
    hid[t] = acc > 0.f ? acc : 0.f;
    __syncthreads();
    if(t < CC){
        float a = fc2b[t];
        #pragma unroll
        for(int p = 0; p < PENN; ++p) a = fmaf(hid[p], fc2w[t*PENN + p], a);
        logit[t] = a;
    }
    __syncthreads();
    if(t < CC){
        float m = logit[0];
        #pragma unroll
        for(int c = 1; c < CC; ++c) m = fmaxf(m, logit[c]);
        float se = 0.f;
        #pragma unroll
        for(int c = 0; c < CC; ++c) se += expf(logit[c] - m);
        out[r*CC + t] = logit[t] - m - logf(se);
    }
}

extern "C" void kernel_launch(void* const* d_in, const int* in_sizes, int n_in,
                              void* d_out, int out_size, void* d_ws, size_t ws_size,
                              hipStream_t stream){
    const float* x      = (const float*)d_in[0];
    const int*   edges  = (const int*)d_in[1];
    const int*   batch  = (const int*)d_in[2];
    const float* adjh   = (const float*)d_in[3];
    const float* fh     = (const float*)d_in[4];   // z0
    const float* fc_w   = (const float*)d_in[5];
    const float* fc_b   = (const float*)d_in[6];
    const float* rw_w   = (const float*)d_in[7];
    const float* rw_b   = (const float*)d_in[8];
    const float* gamma  = (const float*)d_in[9];
    const float* beta   = (const float*)d_in[10];
    const float* fc1w   = (const float*)d_in[11];
    const float* fc1b   = (const float*)d_in[12];
    const float* fc2w   = (const float*)d_in[13];
    const float* fc2b   = (const float*)d_in[14];
    float* out = (float*)d_out;

    const int* row = edges;
    const int* col = edges + E_EDGES;

    // workspace carve-up
    size_t off = 0;
    auto alloc_f = [&](size_t nf) -> float* {
        float* p = (float*)((char*)d_ws + off);
        off += nf * sizeof(float);
        off = (off + 255) & ~(size_t)255;
        return p;
    };
    float* xh     = alloc_f((size_t)N_NODES*DD);
    float* ybuf   = alloc_f((size_t)N_NODES*DD);
    float* ybuf2  = alloc_f((size_t)N_NODES*DD);
    float* cur1   = alloc_f((size_t)N_NODES*DD);
    float* cur2   = alloc_f((size_t)N_NODES*DD);
    float* A1g    = alloc_f(HH*SS*SS);
    float* A2g    = alloc_f(HH*SS*SS);
    float* P      = alloc_f((size_t)3*GG*HS);
    float* outp   = alloc_f((size_t)GG*F_OUT);
    float* scl    = alloc_f(F_OUT);
    float* shf    = alloc_f(F_OUT);
    int*   start  = (int*)alloc_f(GG + 1);
    int*   cnt_r  = (int*)alloc_f(N_NODES);
    int*   cnt_c  = (int*)alloc_f(N_NODES);
    int*   rowptr = (int*)alloc_f(N_NODES + 1);
    int*   cursor = (int*)alloc_f(N_NODES);
    int*   bsum   = (int*)alloc_f(NBLK_SCAN);
    int*   boff   = (int*)alloc_f(NBLK_SCAN);
    int*   erow   = (int*)alloc_f(E_EDGES);

    int blkN = (N_NODES + 255)/256;
    int blkE = (E_EDGES + 255)/256;

    // degree + CSR build (edge-structure only; reused by both gathers)
    k_zero_cnts<<<blkN, 256, 0, stream>>>(cnt_r, cnt_c);
    k_deg_hist<<<blkE, 256, 0, stream>>>(row, col, cnt_r, cnt_c);
    k_scan_bsum<<<NBLK_SCAN, 256, 0, stream>>>(cnt_c, bsum);
    k_scan_boff<<<1, 512, 0, stream>>>(bsum, boff, rowptr);
    k_scan_final<<<NBLK_SCAN, 256, 0, stream>>>(cnt_c, boff, rowptr, cursor);
    k_fill<<<blkE, 256, 0, stream>>>(row, col, cursor, erow);

    k_xh<<<1024, 256, 0, stream>>>(x, fc_w, fc_b, cnt_r, xh, ybuf);
    k_gather_lin<<<2048, 256, 0, stream>>>(rowptr, erow, ybuf,  rw_w,         rw_b,      cnt_r, cur1, ybuf2, 1);
    k_gather_lin<<<2048, 256, 0, stream>>>(rowptr, erow, ybuf2, rw_w + DD*DD, rw_b + DD, cnt_r, cur2, nullptr, 0);

    k_adj<<<1, 256, 0, stream>>>(adjh, A1g, A2g);
    k_bounds<<<blkN, 256, 0, stream>>>(batch, start);
    k_zero_P<<<(3*GG*HS + 255)/256, 256, 0, stream>>>(P);
    k_feat<<<GSPLIT*GG, 256, 0, stream>>>(fh, A1g, A2g, xh, cur1, cur2, start, P);
    k_outpre<<<(GG*F_OUT + 255)/256, 256, 0, stream>>>(P, outp);
    k_bnstats<<<F_OUT, 64, 0, stream>>>(outp, gamma, beta, scl, shf);
    k_mlp<<<GG, 128, 0, stream>>>(outp, scl, shf, fc1w, fc1b, fc2w, fc2b, out);
}